// Round 1
// baseline (850.730 us; speedup 1.0000x reference)
//
#include <hip/hip_runtime.h>

#define H 256
#define W 256
#define BS 8
#define IC 16          // in_ch (flow fields per batch; also out channels)
#define OCH 32         // conv output channels = 2*IC
#define NSTEPS 7
#define PLANE (H*W)            // 65536
#define NFIELDS (BS*IC)        // 128
#define BN_N (BS*PLANE)        // 524288 elements per BN channel
#define BN_EPS 1e-5f

// ---------------------------------------------------------------------------
// K0: transpose vec_w [oc][ic][3][3] -> wT [ic*9+k][oc]  (contiguous over oc)
// ---------------------------------------------------------------------------
__global__ void transpose_w_kernel(const float* __restrict__ w,
                                   float* __restrict__ wT) {
    for (int idx = threadIdx.x; idx < OCH * IC * 9; idx += blockDim.x) {
        int oc  = idx / (IC * 9);
        int rem = idx - oc * (IC * 9);   // ic*9 + k
        wT[rem * OCH + oc] = w[idx];
    }
}

// ---------------------------------------------------------------------------
// K1: 3x3 conv (16->32) + bias. Output interleaved float2 per field:
//     vec[(b*IC+c)][h][w] = {conv_ch(2c), conv_ch(2c+1)}
// Block: (b, 16x16 output tile). Thread: one pixel, all 32 oc.
// ---------------------------------------------------------------------------
__global__ __launch_bounds__(256) void conv_kernel(
    const float* __restrict__ f, const float* __restrict__ wT,
    const float* __restrict__ vec_b, float2* __restrict__ vec_out) {
    __shared__ float sf[IC][18][18];   // 20.7 KB input patch

    int blk = blockIdx.x;              // BS*16*16 = 2048
    int b   = blk >> 8;
    int ty0 = ((blk >> 4) & 15) * 16;
    int tx0 = (blk & 15) * 16;
    int tid = threadIdx.x;

    // stage the 18x18x16 input patch (zero-padded)
    for (int idx = tid; idx < IC * 18 * 18; idx += 256) {
        int ic  = idx / 324;
        int rem = idx - ic * 324;
        int r   = rem / 18;
        int cc  = rem - r * 18;
        int gy = ty0 - 1 + r, gx = tx0 - 1 + cc;
        float v = 0.f;
        if (gy >= 0 && gy < H && gx >= 0 && gx < W)
            v = f[((size_t)(b * IC + ic) * H + gy) * W + gx];
        sf[ic][r][cc] = v;
    }
    __syncthreads();

    int ty = tid >> 4, tx = tid & 15;
    float acc[OCH];
#pragma unroll
    for (int oc = 0; oc < OCH; ++oc) acc[oc] = vec_b[oc];

    for (int ic = 0; ic < IC; ++ic) {
#pragma unroll
        for (int k = 0; k < 9; ++k) {
            int ky = k / 3, kx = k - ky * 3;
            float fv = sf[ic][ty + ky][tx + kx];
            const float* wrow = wT + (ic * 9 + k) * OCH;  // uniform -> s_load
#pragma unroll
            for (int oc = 0; oc < OCH; ++oc)
                acc[oc] = fmaf(fv, wrow[oc], acc[oc]);
        }
    }

    int y = ty0 + ty, x = tx0 + tx;
#pragma unroll
    for (int c = 0; c < IC; ++c) {
        vec_out[(size_t)(b * IC + c) * PLANE + y * W + x] =
            make_float2(acc[2 * c], acc[2 * c + 1]);
    }
}

// ---------------------------------------------------------------------------
// K2: per-channel sum / sumsq over the interleaved conv output.
// stats[0..31] = sum(ch), stats[32..63] = sumsq(ch). (zeroed beforehand)
// ---------------------------------------------------------------------------
__global__ __launch_bounds__(256) void stats_kernel(
    const float2* __restrict__ vec, float* __restrict__ stats) {
    int blk   = blockIdx.x;            // NFIELDS*16 = 2048
    int n     = blk >> 4;
    int chunk = blk & 15;
    const float2* p = vec + (size_t)n * PLANE + chunk * 4096;
    int tid = threadIdx.x;

    float s0 = 0.f, s1 = 0.f, q0 = 0.f, q1 = 0.f;
#pragma unroll 4
    for (int i = tid; i < 4096; i += 256) {
        float2 v = p[i];
        s0 += v.x; s1 += v.y;
        q0 = fmaf(v.x, v.x, q0);
        q1 = fmaf(v.y, v.y, q1);
    }
#pragma unroll
    for (int off = 32; off > 0; off >>= 1) {
        s0 += __shfl_down(s0, off, 64);
        s1 += __shfl_down(s1, off, 64);
        q0 += __shfl_down(q0, off, 64);
        q1 += __shfl_down(q1, off, 64);
    }
    __shared__ float red[4][4];
    int wave = tid >> 6, lane = tid & 63;
    if (lane == 0) {
        red[wave][0] = s0; red[wave][1] = s1;
        red[wave][2] = q0; red[wave][3] = q1;
    }
    __syncthreads();
    if (tid == 0) {
        float t0 = 0.f, t1 = 0.f, t2 = 0.f, t3 = 0.f;
#pragma unroll
        for (int wv = 0; wv < 4; ++wv) {
            t0 += red[wv][0]; t1 += red[wv][1];
            t2 += red[wv][2]; t3 += red[wv][3];
        }
        int ch0 = 2 * (n & 15);
        atomicAdd(stats + ch0,          t0);
        atomicAdd(stats + ch0 + 1,      t1);
        atomicAdd(stats + 32 + ch0,     t2);
        atomicAdd(stats + 32 + ch0 + 1, t3);
    }
}

// ---------------------------------------------------------------------------
// K3: fold BN (training-mode batch stats) + 1/128 scale into per-channel
//     affine: vec0 = A[ch]*conv + B[ch].  AB[0..31]=A, AB[32..63]=B.
// ---------------------------------------------------------------------------
__global__ void finalize_kernel(const float* __restrict__ stats,
                                const float* __restrict__ gamma,
                                const float* __restrict__ beta,
                                float* __restrict__ AB) {
    int ch = threadIdx.x;
    if (ch < 2 * IC) {
        const float invN = 1.f / (float)BN_N;
        float mean = stats[ch] * invN;
        float var  = stats[32 + ch] * invN - mean * mean;
        float rs   = rsqrtf(var + BN_EPS);
        float a    = gamma[ch] * rs;
        AB[ch]      = a * (1.f / 128.f);
        AB[32 + ch] = (beta[ch] - a * mean) * (1.f / 128.f);
    }
}

// ---------------------------------------------------------------------------
// bilinear sample of a single-channel plane, zero padding outside
// ---------------------------------------------------------------------------
__device__ __forceinline__ float bilin1(const float* __restrict__ p,
                                        float py, float px) {
    float ffy = floorf(py), ffx = floorf(px);
    int y0 = (int)ffy, x0 = (int)ffx;
    int y1 = y0 + 1, x1 = x0 + 1;
    float wy1 = py - ffy, wy0 = 1.f - wy1;
    float wx1 = px - ffx, wx0 = 1.f - wx1;
    bool vy0 = (unsigned)y0 < (unsigned)H, vy1 = (unsigned)y1 < (unsigned)H;
    bool vx0 = (unsigned)x0 < (unsigned)W, vx1 = (unsigned)x1 < (unsigned)W;
    float v00 = (vy0 && vx0) ? p[y0 * W + x0] : 0.f;
    float v01 = (vy0 && vx1) ? p[y0 * W + x1] : 0.f;
    float v10 = (vy1 && vx0) ? p[y1 * W + x0] : 0.f;
    float v11 = (vy1 && vx1) ? p[y1 * W + x1] : 0.f;
    return wy0 * (wx0 * v00 + wx1 * v01) + wy1 * (wx0 * v10 + wx1 * v11);
}

// ---------------------------------------------------------------------------
// K4: one scaling-and-squaring step, fused with the map-warp of f and the
//     per-pixel 16x16 fuse matvec accumulated into out.
// Block = (b, row h), thread = pixel column. step==0 applies the BN affine
// on every read of the raw conv field (incl. taps: invalid taps stay 0).
// ---------------------------------------------------------------------------
__global__ __launch_bounds__(256) void step_kernel(
    const float2* __restrict__ vin, float2* __restrict__ vout,
    const float* __restrict__ f, const float* __restrict__ AB,
    const float* __restrict__ fw, const float* __restrict__ fb,
    float* __restrict__ out, int step) {
    __shared__ float lds_m[IC * W];   // 16 KB: warped-f value per (c, pixel)

    int blk = blockIdx.x;             // BS*H = 2048
    int b   = blk >> 8;
    int h   = blk & (H - 1);
    int tx  = threadIdx.x;

#pragma unroll 2
    for (int c = 0; c < IC; ++c) {
        float a0 = 1.f, b0 = 0.f, a1 = 1.f, b1 = 0.f;
        if (step == 0) {
            a0 = AB[2 * c];     b0 = AB[32 + 2 * c];
            a1 = AB[2 * c + 1]; b1 = AB[32 + 2 * c + 1];
        }
        const float2* plane = vin + (size_t)(b * IC + c) * PLANE;
        float2 v = plane[h * W + tx];
        float fy = fmaf(a0, v.x, b0);    // flow comp 0 (y)
        float fx = fmaf(a1, v.y, b1);    // flow comp 1 (x)
        float py = (float)h + fy, px = (float)tx + fx;

        float ffy = floorf(py), ffx = floorf(px);
        int y0 = (int)ffy, x0 = (int)ffx;
        int y1 = y0 + 1, x1 = x0 + 1;
        float wy1 = py - ffy, wy0 = 1.f - wy1;
        float wx1 = px - ffx, wx0 = 1.f - wx1;
        bool vy0 = (unsigned)y0 < (unsigned)H, vy1 = (unsigned)y1 < (unsigned)H;
        bool vx0 = (unsigned)x0 < (unsigned)W, vx1 = (unsigned)x1 < (unsigned)W;

        float sy = 0.f, sx = 0.f;
        if (vy0 && vx0) {
            float2 t = plane[y0 * W + x0]; float wg = wy0 * wx0;
            sy = fmaf(wg, fmaf(a0, t.x, b0), sy);
            sx = fmaf(wg, fmaf(a1, t.y, b1), sx);
        }
        if (vy0 && vx1) {
            float2 t = plane[y0 * W + x1]; float wg = wy0 * wx1;
            sy = fmaf(wg, fmaf(a0, t.x, b0), sy);
            sx = fmaf(wg, fmaf(a1, t.y, b1), sx);
        }
        if (vy1 && vx0) {
            float2 t = plane[y1 * W + x0]; float wg = wy1 * wx0;
            sy = fmaf(wg, fmaf(a0, t.x, b0), sy);
            sx = fmaf(wg, fmaf(a1, t.y, b1), sx);
        }
        if (vy1 && vx1) {
            float2 t = plane[y1 * W + x1]; float wg = wy1 * wx1;
            sy = fmaf(wg, fmaf(a0, t.x, b0), sy);
            sx = fmaf(wg, fmaf(a1, t.y, b1), sx);
        }

        float ny = fy + sy;   // new deform (this step's d_s)
        float nx = fx + sx;
        vout[(size_t)(b * IC + c) * PLANE + h * W + tx] = make_float2(ny, nx);

        // fused map step: warp f[b,c] by the fresh deform
        const float* fplane = f + (size_t)(b * IC + c) * PLANE;
        lds_m[c * W + tx] = bilin1(fplane, (float)h + ny, (float)tx + nx);
    }
    // each thread only touches its own lds_m column -> no barrier needed

    float mreg[IC];
#pragma unroll
    for (int c = 0; c < IC; ++c) mreg[c] = lds_m[c * W + tx];

#pragma unroll 1
    for (int o = 0; o < IC; ++o) {
        float acc = 0.f;
#pragma unroll
        for (int c = 0; c < IC; ++c)
            acc = fmaf(fw[(o * IC + c) * NSTEPS + step], mreg[c], acc);
        size_t oidx = ((size_t)(b * IC + o) * H + h) * W + tx;
        if (step == 0) out[oidx] = acc + fb[o];
        else           out[oidx] += acc;
    }
}

// ---------------------------------------------------------------------------
extern "C" void kernel_launch(void* const* d_in, const int* in_sizes, int n_in,
                              void* d_out, int out_size, void* d_ws,
                              size_t ws_size, hipStream_t stream) {
    const float* f      = (const float*)d_in[0];
    const float* vec_w  = (const float*)d_in[1];
    const float* vec_b  = (const float*)d_in[2];
    const float* gamma  = (const float*)d_in[3];
    const float* beta   = (const float*)d_in[4];
    const float* fuse_w = (const float*)d_in[5];
    const float* fuse_b = (const float*)d_in[6];
    float* out = (float*)d_out;

    // workspace layout (floats):
    //   buf0: NFIELDS*PLANE float2  (67.1 MB)
    //   buf1: NFIELDS*PLANE float2  (67.1 MB)
    //   wT:   4608
    //   stats: sum[32] sumsq[32] A[32] B[32]
    float* ws = (float*)d_ws;
    const size_t bufElems = (size_t)NFIELDS * PLANE * 2;  // floats per buffer
    float2* buf0 = (float2*)ws;
    float2* buf1 = (float2*)(ws + bufElems);
    float*  wT   = ws + 2 * bufElems;
    float*  stats = wT + OCH * IC * 9;

    hipMemsetAsync(stats, 0, 64 * sizeof(float), stream);
    transpose_w_kernel<<<1, 512, 0, stream>>>(vec_w, wT);
    conv_kernel<<<BS * 16 * 16, 256, 0, stream>>>(f, wT, vec_b, buf0);
    stats_kernel<<<NFIELDS * 16, 256, 0, stream>>>(buf0, stats);
    finalize_kernel<<<1, 64, 0, stream>>>(stats, gamma, beta, stats + 64);

    float2* vin = buf0;
    float2* vout = buf1;
    for (int s = 0; s < NSTEPS; ++s) {
        step_kernel<<<BS * H, 256, 0, stream>>>(vin, vout, f, stats + 64,
                                                fuse_w, fuse_b, out, s);
        float2* t = vin; vin = vout; vout = t;
    }
}

// Round 2
// 695.141 us; speedup vs baseline: 1.2238x; 1.2238x over previous
//
#include <hip/hip_runtime.h>

#define H 256
#define W 256
#define BS 8
#define IC 16          // in_ch (flow fields per batch; also out channels)
#define OCH 32         // conv output channels = 2*IC
#define NSTEPS 7
#define PLANE (H*W)            // 65536
#define NFIELDS (BS*IC)        // 128
#define BN_N (BS*PLANE)        // 524288 elements per BN channel
#define BN_EPS 1e-5f

// ---------------------------------------------------------------------------
// K0: transpose vec_w [oc][ic][3][3] -> wT [ic*9+k][oc]  (contiguous over oc)
// ---------------------------------------------------------------------------
__global__ void transpose_w_kernel(const float* __restrict__ w,
                                   float* __restrict__ wT) {
    for (int idx = threadIdx.x; idx < OCH * IC * 9; idx += blockDim.x) {
        int oc  = idx / (IC * 9);
        int rem = idx - oc * (IC * 9);   // ic*9 + k
        wT[rem * OCH + oc] = w[idx];
    }
}

// ---------------------------------------------------------------------------
// K1: 3x3 conv (16->32) + bias. 32x16 output tile, 2 pixels per thread.
// Output interleaved float2 per field.
// ---------------------------------------------------------------------------
__global__ __launch_bounds__(256) void conv_kernel(
    const float* __restrict__ f, const float* __restrict__ wT,
    const float* __restrict__ vec_b, float2* __restrict__ vec_out) {
    __shared__ float sf[IC][18][34];   // 39.2 KB input patch

    int blk = blockIdx.x;              // 8 * 16 * 8 = 1024
    int b   = blk >> 7;
    int rem = blk & 127;
    int ty0 = (rem >> 3) * 16;
    int tx0 = (rem & 7) * 32;
    int tid = threadIdx.x;

    // stage the 18x34x16 input patch (zero-padded)
    for (int idx = tid; idx < IC * 18 * 34; idx += 256) {
        int ic  = idx / 612;
        int r2  = idx - ic * 612;
        int r   = r2 / 34;
        int cc  = r2 - r * 34;
        int gy = ty0 - 1 + r, gx = tx0 - 1 + cc;
        float v = 0.f;
        if (gy >= 0 && gy < H && gx >= 0 && gx < W)
            v = f[((size_t)(b * IC + ic) * H + gy) * W + gx];
        sf[ic][r][cc] = v;
    }
    __syncthreads();

    int tyl = tid >> 5, txl = tid & 31;   // tyl 0..7, txl 0..31
    float acc0[OCH], acc1[OCH];
#pragma unroll
    for (int oc = 0; oc < OCH; ++oc) { acc0[oc] = vec_b[oc]; acc1[oc] = vec_b[oc]; }

    for (int ic = 0; ic < IC; ++ic) {
#pragma unroll
        for (int k = 0; k < 9; ++k) {
            int ky = k / 3, kx = k - ky * 3;
            float fv0 = sf[ic][tyl + ky][txl + kx];
            float fv1 = sf[ic][tyl + 8 + ky][txl + kx];
            const float* wrow = wT + (ic * 9 + k) * OCH;  // wave-uniform
#pragma unroll
            for (int oc = 0; oc < OCH; ++oc) {
                float wv = wrow[oc];
                acc0[oc] = fmaf(fv0, wv, acc0[oc]);
                acc1[oc] = fmaf(fv1, wv, acc1[oc]);
            }
        }
    }

    int y0p = ty0 + tyl, y1p = ty0 + tyl + 8, x = tx0 + txl;
#pragma unroll
    for (int c = 0; c < IC; ++c) {
        size_t pb = (size_t)(b * IC + c) * PLANE;
        vec_out[pb + y0p * W + x] = make_float2(acc0[2 * c], acc0[2 * c + 1]);
        vec_out[pb + y1p * W + x] = make_float2(acc1[2 * c], acc1[2 * c + 1]);
    }
}

// ---------------------------------------------------------------------------
// K2: per-channel sum / sumsq over the interleaved conv output.
// ---------------------------------------------------------------------------
__global__ __launch_bounds__(256) void stats_kernel(
    const float2* __restrict__ vec, float* __restrict__ stats) {
    int blk   = blockIdx.x;            // NFIELDS*16 = 2048
    int n     = blk >> 4;
    int chunk = blk & 15;
    const float4* p = (const float4*)(vec + (size_t)n * PLANE) + chunk * 2048;
    int tid = threadIdx.x;

    float s0 = 0.f, s1 = 0.f, q0 = 0.f, q1 = 0.f;
#pragma unroll 4
    for (int i = tid; i < 2048; i += 256) {
        float4 v = p[i];
        s0 += v.x + v.z; s1 += v.y + v.w;
        q0 = fmaf(v.x, v.x, fmaf(v.z, v.z, q0));
        q1 = fmaf(v.y, v.y, fmaf(v.w, v.w, q1));
    }
#pragma unroll
    for (int off = 32; off > 0; off >>= 1) {
        s0 += __shfl_down(s0, off, 64);
        s1 += __shfl_down(s1, off, 64);
        q0 += __shfl_down(q0, off, 64);
        q1 += __shfl_down(q1, off, 64);
    }
    __shared__ float red[4][4];
    int wave = tid >> 6, lane = tid & 63;
    if (lane == 0) {
        red[wave][0] = s0; red[wave][1] = s1;
        red[wave][2] = q0; red[wave][3] = q1;
    }
    __syncthreads();
    if (tid == 0) {
        float t0 = 0.f, t1 = 0.f, t2 = 0.f, t3 = 0.f;
#pragma unroll
        for (int wv = 0; wv < 4; ++wv) {
            t0 += red[wv][0]; t1 += red[wv][1];
            t2 += red[wv][2]; t3 += red[wv][3];
        }
        int ch0 = 2 * (n & 15);
        atomicAdd(stats + ch0,          t0);
        atomicAdd(stats + ch0 + 1,      t1);
        atomicAdd(stats + 32 + ch0,     t2);
        atomicAdd(stats + 32 + ch0 + 1, t3);
    }
}

// ---------------------------------------------------------------------------
// K3: fold BN + 1/128 scale into per-channel affine.
// ---------------------------------------------------------------------------
__global__ void finalize_kernel(const float* __restrict__ stats,
                                const float* __restrict__ gamma,
                                const float* __restrict__ beta,
                                float* __restrict__ AB) {
    int ch = threadIdx.x;
    if (ch < 2 * IC) {
        const float invN = 1.f / (float)BN_N;
        float mean = stats[ch] * invN;
        float var  = stats[32 + ch] * invN - mean * mean;
        float rs   = rsqrtf(var + BN_EPS);
        float a    = gamma[ch] * rs;
        AB[ch]      = a * (1.f / 128.f);
        AB[32 + ch] = (beta[ch] - a * mean) * (1.f / 128.f);
    }
}

// ---------------------------------------------------------------------------
// K4: one scaling-and-squaring step + fused map-warp of f + fuse matvec.
// Branch-free clamped-address gathers (validity folded into weights).
// Channels processed in groups of 4 for memory-level parallelism.
// ---------------------------------------------------------------------------
template <bool FIRST, bool LAST>
__global__ __launch_bounds__(256) void step_kernel(
    const float2* __restrict__ vin, float2* __restrict__ vout,
    const float* __restrict__ f, const float* __restrict__ AB,
    const float* __restrict__ fw, const float* __restrict__ fb,
    float* __restrict__ out, int step) {
    int blk = blockIdx.x;             // BS*H = 2048
    int b   = blk >> 8;
    int h   = blk & (H - 1);
    int tx  = threadIdx.x;
    int idx = h * W + tx;
    const size_t base = (size_t)b * IC * PLANE;

    float mv[IC];   // warped-f values per channel (registers; no LDS)

#pragma unroll 2
    for (int g = 0; g < 4; ++g) {
        float a0j[4], b0j[4], a1j[4], b1j[4];
        float fy[4], fx[4];
        int   o00[4], o01[4], o10[4], o11[4];
        float w00[4], w01[4], w10[4], w11[4];
        const float2* pl[4];
        float2 vc[4];

        // --- center loads (4 independent) ---
#pragma unroll
        for (int j = 0; j < 4; ++j) {
            int c = 4 * g + j;
            pl[j] = vin + base + (size_t)c * PLANE;
            vc[j] = pl[j][idx];
        }

        // --- tap setup: clamped offsets + masked weights ---
#pragma unroll
        for (int j = 0; j < 4; ++j) {
            int c = 4 * g + j;
            if (FIRST) {
                a0j[j] = AB[2 * c];     b0j[j] = AB[32 + 2 * c];
                a1j[j] = AB[2 * c + 1]; b1j[j] = AB[32 + 2 * c + 1];
            }
            fy[j] = FIRST ? fmaf(a0j[j], vc[j].x, b0j[j]) : vc[j].x;
            fx[j] = FIRST ? fmaf(a1j[j], vc[j].y, b1j[j]) : vc[j].y;
            float py = (float)h + fy[j], px = (float)tx + fx[j];
            float ffy = floorf(py), ffx = floorf(px);
            int y0 = (int)ffy, x0 = (int)ffx;
            float wy1 = py - ffy, wy0 = 1.f - wy1;
            float wx1 = px - ffx, wx0 = 1.f - wx1;
            bool vy0 = (unsigned)y0 < (unsigned)H, vy1 = (unsigned)(y0 + 1) < (unsigned)H;
            bool vx0 = (unsigned)x0 < (unsigned)W, vx1 = (unsigned)(x0 + 1) < (unsigned)W;
            int yc0 = min(max(y0, 0), H - 1), yc1 = min(max(y0 + 1, 0), H - 1);
            int xc0 = min(max(x0, 0), W - 1), xc1 = min(max(x0 + 1, 0), W - 1);
            o00[j] = yc0 * W + xc0; o01[j] = yc0 * W + xc1;
            o10[j] = yc1 * W + xc0; o11[j] = yc1 * W + xc1;
            w00[j] = (vy0 && vx0) ? wy0 * wx0 : 0.f;
            w01[j] = (vy0 && vx1) ? wy0 * wx1 : 0.f;
            w10[j] = (vy1 && vx0) ? wy1 * wx0 : 0.f;
            w11[j] = (vy1 && vx1) ? wy1 * wx1 : 0.f;
        }

        // --- 16 unconditional tap loads ---
        float2 t00[4], t01[4], t10[4], t11[4];
#pragma unroll
        for (int j = 0; j < 4; ++j) {
            t00[j] = pl[j][o00[j]]; t01[j] = pl[j][o01[j]];
            t10[j] = pl[j][o10[j]]; t11[j] = pl[j][o11[j]];
        }

        // --- combine, write vout, set up f-gather ---
        float ny[4], nx[4];
        int   p00[4], p01[4], p10[4], p11[4];
        float u00[4], u01[4], u10[4], u11[4];
#pragma unroll
        for (int j = 0; j < 4; ++j) {
            float sy, sx;
            if (FIRST) {
                sy = w00[j] * fmaf(a0j[j], t00[j].x, b0j[j])
                   + w01[j] * fmaf(a0j[j], t01[j].x, b0j[j])
                   + w10[j] * fmaf(a0j[j], t10[j].x, b0j[j])
                   + w11[j] * fmaf(a0j[j], t11[j].x, b0j[j]);
                sx = w00[j] * fmaf(a1j[j], t00[j].y, b1j[j])
                   + w01[j] * fmaf(a1j[j], t01[j].y, b1j[j])
                   + w10[j] * fmaf(a1j[j], t10[j].y, b1j[j])
                   + w11[j] * fmaf(a1j[j], t11[j].y, b1j[j]);
            } else {
                sy = w00[j] * t00[j].x + w01[j] * t01[j].x
                   + w10[j] * t10[j].x + w11[j] * t11[j].x;
                sx = w00[j] * t00[j].y + w01[j] * t01[j].y
                   + w10[j] * t10[j].y + w11[j] * t11[j].y;
            }
            ny[j] = fy[j] + sy;
            nx[j] = fx[j] + sx;
            int c = 4 * g + j;
            if (!LAST)
                vout[base + (size_t)c * PLANE + idx] = make_float2(ny[j], nx[j]);

            float py = (float)h + ny[j], px = (float)tx + nx[j];
            float ffy = floorf(py), ffx = floorf(px);
            int y0 = (int)ffy, x0 = (int)ffx;
            float wy1 = py - ffy, wy0 = 1.f - wy1;
            float wx1 = px - ffx, wx0 = 1.f - wx1;
            bool vy0 = (unsigned)y0 < (unsigned)H, vy1 = (unsigned)(y0 + 1) < (unsigned)H;
            bool vx0 = (unsigned)x0 < (unsigned)W, vx1 = (unsigned)(x0 + 1) < (unsigned)W;
            int yc0 = min(max(y0, 0), H - 1), yc1 = min(max(y0 + 1, 0), H - 1);
            int xc0 = min(max(x0, 0), W - 1), xc1 = min(max(x0 + 1, 0), W - 1);
            p00[j] = yc0 * W + xc0; p01[j] = yc0 * W + xc1;
            p10[j] = yc1 * W + xc0; p11[j] = yc1 * W + xc1;
            u00[j] = (vy0 && vx0) ? wy0 * wx0 : 0.f;
            u01[j] = (vy0 && vx1) ? wy0 * wx1 : 0.f;
            u10[j] = (vy1 && vx0) ? wy1 * wx0 : 0.f;
            u11[j] = (vy1 && vx1) ? wy1 * wx1 : 0.f;
        }

        // --- 16 unconditional f-tap loads + combine ---
#pragma unroll
        for (int j = 0; j < 4; ++j) {
            int c = 4 * g + j;
            const float* fp = f + base + (size_t)c * PLANE;
            float f00 = fp[p00[j]], f01 = fp[p01[j]];
            float f10 = fp[p10[j]], f11 = fp[p11[j]];
            mv[c] = u00[j] * f00 + u01[j] * f01 + u10[j] * f10 + u11[j] * f11;
        }
    }

    // --- fuse matvec: out_o (+)= sum_c fw[o,c,step] * mv[c] ---
    float prev[IC];
    if (!FIRST) {
#pragma unroll
        for (int o = 0; o < IC; ++o)
            prev[o] = out[base + (size_t)o * PLANE + idx];
    }
#pragma unroll
    for (int o = 0; o < IC; ++o) {
        float acc = FIRST ? fb[o] : prev[o];
#pragma unroll
        for (int c = 0; c < IC; ++c)
            acc = fmaf(fw[(o * IC + c) * NSTEPS + step], mv[c], acc);
        out[base + (size_t)o * PLANE + idx] = acc;
    }
}

// ---------------------------------------------------------------------------
extern "C" void kernel_launch(void* const* d_in, const int* in_sizes, int n_in,
                              void* d_out, int out_size, void* d_ws,
                              size_t ws_size, hipStream_t stream) {
    const float* f      = (const float*)d_in[0];
    const float* vec_w  = (const float*)d_in[1];
    const float* vec_b  = (const float*)d_in[2];
    const float* gamma  = (const float*)d_in[3];
    const float* beta   = (const float*)d_in[4];
    const float* fuse_w = (const float*)d_in[5];
    const float* fuse_b = (const float*)d_in[6];
    float* out = (float*)d_out;

    float* ws = (float*)d_ws;
    const size_t bufElems = (size_t)NFIELDS * PLANE * 2;  // floats per buffer
    float2* buf0 = (float2*)ws;
    float2* buf1 = (float2*)(ws + bufElems);
    float*  wT   = ws + 2 * bufElems;
    float*  stats = wT + OCH * IC * 9;

    hipMemsetAsync(stats, 0, 64 * sizeof(float), stream);
    transpose_w_kernel<<<1, 512, 0, stream>>>(vec_w, wT);
    conv_kernel<<<1024, 256, 0, stream>>>(f, wT, vec_b, buf0);
    stats_kernel<<<NFIELDS * 16, 256, 0, stream>>>(buf0, stats);
    finalize_kernel<<<1, 64, 0, stream>>>(stats, gamma, beta, stats + 64);

    float2* vin = buf0;
    float2* vout = buf1;
    for (int s = 0; s < NSTEPS; ++s) {
        if (s == 0)
            step_kernel<true, false><<<BS * H, 256, 0, stream>>>(
                vin, vout, f, stats + 64, fuse_w, fuse_b, out, s);
        else if (s < NSTEPS - 1)
            step_kernel<false, false><<<BS * H, 256, 0, stream>>>(
                vin, vout, f, stats + 64, fuse_w, fuse_b, out, s);
        else
            step_kernel<false, true><<<BS * H, 256, 0, stream>>>(
                vin, vout, f, stats + 64, fuse_w, fuse_b, out, s);
        float2* t = vin; vin = vout; vout = t;
    }
}

// Round 4
// 694.647 us; speedup vs baseline: 1.2247x; 1.0007x over previous
//
#include <hip/hip_runtime.h>
#include <hip/hip_cooperative_groups.h>

namespace cg = cooperative_groups;

#define H 256
#define W 256
#define BS 8
#define IC 16          // in_ch (flow fields per batch; also out channels)
#define OCH 32         // conv output channels = 2*IC
#define NSTEPS 7
#define PLANE (H*W)            // 65536
#define NFIELDS (BS*IC)        // 128
#define BN_N (BS*PLANE)        // 524288 elements per BN channel
#define BN_EPS 1e-5f
#define NCU 256                // gfx950 CU count

// ---------------------------------------------------------------------------
// K0: transpose vec_w [oc][ic][3][3] -> wT [ic*9+k][oc]  (contiguous over oc)
// ---------------------------------------------------------------------------
__global__ void transpose_w_kernel(const float* __restrict__ w,
                                   float* __restrict__ wT) {
    for (int idx = threadIdx.x; idx < OCH * IC * 9; idx += blockDim.x) {
        int oc  = idx / (IC * 9);
        int rem = idx - oc * (IC * 9);   // ic*9 + k
        wT[rem * OCH + oc] = w[idx];
    }
}

// ---------------------------------------------------------------------------
// K1: 3x3 conv (16->32) + bias. 16x16 tile, 1 px/thread, input staged in two
// 8-channel halves (10.9 KB LDS). launch_bounds(256,6): VGPR<=85, 6 blk/CU.
// ---------------------------------------------------------------------------
__global__ __launch_bounds__(256, 6) void conv_kernel(
    const float* __restrict__ f, const float* __restrict__ wT,
    const float* __restrict__ vec_b, float2* __restrict__ vec_out) {
    __shared__ float sf[8][18][19];    // row padded to 19 for bank spread

    int blk = blockIdx.x;              // 8 * 256 = 2048
    int b   = blk >> 8;
    int rem = blk & 255;
    int ty0 = (rem >> 4) * 16;
    int tx0 = (rem & 15) * 16;
    int tid = threadIdx.x;
    int ty  = tid >> 4, tx = tid & 15;

    float acc[OCH];
#pragma unroll
    for (int oc = 0; oc < OCH; ++oc) acc[oc] = vec_b[oc];

    for (int half = 0; half < 2; ++half) {
        if (half) __syncthreads();     // protect LDS overwrite
        for (int idx = tid; idx < 8 * 18 * 18; idx += 256) {
            int ic = idx / 324;
            int r2 = idx - ic * 324;
            int r  = r2 / 18;
            int cc = r2 - r * 18;
            int gy = ty0 - 1 + r, gx = tx0 - 1 + cc;
            float v = 0.f;
            if (gy >= 0 && gy < H && gx >= 0 && gx < W)
                v = f[((size_t)(b * IC + half * 8 + ic) * H + gy) * W + gx];
            sf[ic][r][cc] = v;
        }
        __syncthreads();

#pragma unroll 2
        for (int ic = 0; ic < 8; ++ic) {
#pragma unroll
            for (int k = 0; k < 9; ++k) {
                int ky = k / 3, kx = k - ky * 3;
                float fv = sf[ic][ty + ky][tx + kx];
                const float* wrow = wT + ((half * 8 + ic) * 9 + k) * OCH;
#pragma unroll
                for (int oc = 0; oc < OCH; ++oc)
                    acc[oc] = fmaf(fv, wrow[oc], acc[oc]);
            }
        }
    }

    int y = ty0 + ty, x = tx0 + tx;
#pragma unroll
    for (int c = 0; c < IC; ++c) {
        vec_out[(size_t)(b * IC + c) * PLANE + y * W + x] =
            make_float2(acc[2 * c], acc[2 * c + 1]);
    }
}

// ---------------------------------------------------------------------------
// K2: per-channel sum / sumsq over the interleaved conv output.
// ---------------------------------------------------------------------------
__global__ __launch_bounds__(256) void stats_kernel(
    const float2* __restrict__ vec, float* __restrict__ stats) {
    int blk   = blockIdx.x;            // NFIELDS*16 = 2048
    int n     = blk >> 4;
    int chunk = blk & 15;
    const float4* p = (const float4*)(vec + (size_t)n * PLANE) + chunk * 2048;
    int tid = threadIdx.x;

    float s0 = 0.f, s1 = 0.f, q0 = 0.f, q1 = 0.f;
#pragma unroll 4
    for (int i = tid; i < 2048; i += 256) {
        float4 v = p[i];
        s0 += v.x + v.z; s1 += v.y + v.w;
        q0 = fmaf(v.x, v.x, fmaf(v.z, v.z, q0));
        q1 = fmaf(v.y, v.y, fmaf(v.w, v.w, q1));
    }
#pragma unroll
    for (int off = 32; off > 0; off >>= 1) {
        s0 += __shfl_down(s0, off, 64);
        s1 += __shfl_down(s1, off, 64);
        q0 += __shfl_down(q0, off, 64);
        q1 += __shfl_down(q1, off, 64);
    }
    __shared__ float red[4][4];
    int wave = tid >> 6, lane = tid & 63;
    if (lane == 0) {
        red[wave][0] = s0; red[wave][1] = s1;
        red[wave][2] = q0; red[wave][3] = q1;
    }
    __syncthreads();
    if (tid == 0) {
        float t0 = 0.f, t1 = 0.f, t2 = 0.f, t3 = 0.f;
#pragma unroll
        for (int wv = 0; wv < 4; ++wv) {
            t0 += red[wv][0]; t1 += red[wv][1];
            t2 += red[wv][2]; t3 += red[wv][3];
        }
        int ch0 = 2 * (n & 15);
        atomicAdd(stats + ch0,          t0);
        atomicAdd(stats + ch0 + 1,      t1);
        atomicAdd(stats + 32 + ch0,     t2);
        atomicAdd(stats + 32 + ch0 + 1, t3);
    }
}

// ---------------------------------------------------------------------------
// K3: fold BN + 1/128 scale into per-channel affine (fallback path).
// ---------------------------------------------------------------------------
__global__ void finalize_kernel(const float* __restrict__ stats,
                                const float* __restrict__ gamma,
                                const float* __restrict__ beta,
                                float* __restrict__ AB) {
    int ch = threadIdx.x;
    if (ch < 2 * IC) {
        const float invN = 1.f / (float)BN_N;
        float mean = stats[ch] * invN;
        float var  = stats[32 + ch] * invN - mean * mean;
        float rs   = rsqrtf(var + BN_EPS);
        float a    = gamma[ch] * rs;
        AB[ch]      = a * (1.f / 128.f);
        AB[32 + ch] = (beta[ch] - a * mean) * (1.f / 128.f);
    }
}

// ---------------------------------------------------------------------------
// bilinear tap setup: clamped offsets + validity-masked weights
// ---------------------------------------------------------------------------
__device__ __forceinline__ void tap_setup(float py, float px,
                                          int* o, float* wt) {
    float ffy = floorf(py), ffx = floorf(px);
    int y0 = (int)ffy, x0 = (int)ffx;
    float wy1 = py - ffy, wy0 = 1.f - wy1;
    float wx1 = px - ffx, wx0 = 1.f - wx1;
    bool vy0 = (unsigned)y0 < (unsigned)H, vy1 = (unsigned)(y0 + 1) < (unsigned)H;
    bool vx0 = (unsigned)x0 < (unsigned)W, vx1 = (unsigned)(x0 + 1) < (unsigned)W;
    int yc0 = min(max(y0, 0), H - 1), yc1 = min(max(y0 + 1, 0), H - 1);
    int xc0 = min(max(x0, 0), W - 1), xc1 = min(max(x0 + 1, 0), W - 1);
    o[0] = yc0 * W + xc0; o[1] = yc0 * W + xc1;
    o[2] = yc1 * W + xc0; o[3] = yc1 * W + xc1;
    wt[0] = (vy0 && vx0) ? wy0 * wx0 : 0.f;
    wt[1] = (vy0 && vx1) ? wy0 * wx1 : 0.f;
    wt[2] = (vy1 && vx0) ? wy1 * wx0 : 0.f;
    wt[3] = (vy1 && vx1) ? wy1 * wx1 : 0.f;
}

// ---------------------------------------------------------------------------
// K4-coop: all 7 steps in one cooperative kernel. 512 blocks x 256 threads;
// block owns (b, 4 rows), thread owns 4 pixels. Output accumulator stays in
// registers across all steps (no out RMW). launch_bounds(256,3) -> VGPR<=170
// -> >=3 blocks/CU -> capacity >=768 blocks (strict slack over 512).
// ---------------------------------------------------------------------------
__global__ __launch_bounds__(256, 3) void coop_steps_kernel(
    float2* __restrict__ buf0, float2* __restrict__ buf1,
    const float* __restrict__ f, const float* __restrict__ stats,
    const float* __restrict__ gamma, const float* __restrict__ beta,
    const float* __restrict__ fw, const float* __restrict__ fb,
    float* __restrict__ out) {
    cg::grid_group grid = cg::this_grid();

    __shared__ float sAB[64];     // A[32] (gain/128), B[32] (bias/128)
    __shared__ float sFW[256];    // fw[:,:,s] for the current step

    int tid = threadIdx.x;
    if (tid < 32) {
        const float invN = 1.f / (float)BN_N;
        float mean = stats[tid] * invN;
        float var  = stats[32 + tid] * invN - mean * mean;
        float a    = gamma[tid] * rsqrtf(var + BN_EPS);
        sAB[tid]      = a * (1.f / 128.f);
        sAB[32 + tid] = (beta[tid] - a * mean) * (1.f / 128.f);
    }

    int blk = blockIdx.x;          // 512
    int b   = blk >> 6;            // 64 blocks per batch
    int h0  = (blk & 63) << 2;     // rows h0..h0+3
    int tx  = tid;
    const size_t base = (size_t)b * IC * PLANE;
    int idx[4];
#pragma unroll
    for (int r = 0; r < 4; ++r) idx[r] = (h0 + r) * W + tx;

    float acc[4][IC];
#pragma unroll
    for (int r = 0; r < 4; ++r)
#pragma unroll
        for (int o = 0; o < IC; ++o) acc[r][o] = fb[o];

    for (int s = 0; s < NSTEPS; ++s) {
        const bool first = (s == 0), last = (s == NSTEPS - 1);
        const float2* __restrict__ vin  = (s & 1) ? buf1 : buf0;
        float2* __restrict__       vout = (s & 1) ? buf0 : buf1;

        sFW[tid] = fw[tid * NSTEPS + s];   // tid = o*16+c
        __syncthreads();

        for (int c = 0; c < IC; ++c) {
            const float2* __restrict__ pl = vin + base + (size_t)c * PLANE;
            float2 vc[4];
#pragma unroll
            for (int r = 0; r < 4; ++r) vc[r] = pl[idx[r]];

            float fy[4], fx[4];
            int   o[4][4];
            float wt[4][4];
#pragma unroll
            for (int r = 0; r < 4; ++r) {
                if (first) {
                    fy[r] = fmaf(sAB[2 * c],     vc[r].x, sAB[32 + 2 * c]);
                    fx[r] = fmaf(sAB[2 * c + 1], vc[r].y, sAB[32 + 2 * c + 1]);
                } else {
                    fy[r] = vc[r].x;
                    fx[r] = vc[r].y;
                }
                tap_setup((float)(h0 + r) + fy[r], (float)tx + fx[r],
                          o[r], wt[r]);
            }

            float2 t[4][4];
#pragma unroll
            for (int r = 0; r < 4; ++r)
#pragma unroll
                for (int k = 0; k < 4; ++k) t[r][k] = pl[o[r][k]];

            float ny[4], nx[4];
            int   po[4][4];
            float pw[4][4];
#pragma unroll
            for (int r = 0; r < 4; ++r) {
                float Sy = wt[r][0] * t[r][0].x + wt[r][1] * t[r][1].x
                         + wt[r][2] * t[r][2].x + wt[r][3] * t[r][3].x;
                float Sx = wt[r][0] * t[r][0].y + wt[r][1] * t[r][1].y
                         + wt[r][2] * t[r][2].y + wt[r][3] * t[r][3].y;
                if (first) {
                    float Ws = wt[r][0] + wt[r][1] + wt[r][2] + wt[r][3];
                    ny[r] = fy[r] + fmaf(sAB[2 * c],     Sy, sAB[32 + 2 * c] * Ws);
                    nx[r] = fx[r] + fmaf(sAB[2 * c + 1], Sx, sAB[32 + 2 * c + 1] * Ws);
                } else {
                    ny[r] = fy[r] + Sy;
                    nx[r] = fx[r] + Sx;
                }
                if (!last)
                    vout[base + (size_t)c * PLANE + idx[r]] =
                        make_float2(ny[r], nx[r]);
                tap_setup((float)(h0 + r) + ny[r], (float)tx + nx[r],
                          po[r], pw[r]);
            }

            const float* __restrict__ fp = f + base + (size_t)c * PLANE;
            float m[4];
#pragma unroll
            for (int r = 0; r < 4; ++r)
                m[r] = pw[r][0] * fp[po[r][0]] + pw[r][1] * fp[po[r][1]]
                     + pw[r][2] * fp[po[r][2]] + pw[r][3] * fp[po[r][3]];

#pragma unroll
            for (int r = 0; r < 4; ++r)
#pragma unroll
                for (int oo = 0; oo < IC; ++oo)
                    acc[r][oo] = fmaf(sFW[oo * IC + c], m[r], acc[r][oo]);
        }

        if (!last) {
            __threadfence();
            grid.sync();
            __threadfence();
        }
    }

#pragma unroll
    for (int oo = 0; oo < IC; ++oo)
#pragma unroll
        for (int r = 0; r < 4; ++r)
            out[base + (size_t)oo * PLANE + idx[r]] = acc[r][oo];
}

// ---------------------------------------------------------------------------
// K4-fallback: one step per launch (validated in R2), out RMW per step.
// ---------------------------------------------------------------------------
template <bool FIRST, bool LAST>
__global__ __launch_bounds__(256) void step_kernel(
    const float2* __restrict__ vin, float2* __restrict__ vout,
    const float* __restrict__ f, const float* __restrict__ AB,
    const float* __restrict__ fw, const float* __restrict__ fb,
    float* __restrict__ out, int step) {
    int blk = blockIdx.x;             // BS*H = 2048
    int b   = blk >> 8;
    int h   = blk & (H - 1);
    int tx  = threadIdx.x;
    int idx = h * W + tx;
    const size_t base = (size_t)b * IC * PLANE;

    float mv[IC];

#pragma unroll 2
    for (int g = 0; g < 4; ++g) {
        float a0j[4], b0j[4], a1j[4], b1j[4];
        float fy[4], fx[4];
        int   o[4][4];
        float wt[4][4];
        const float2* pl[4];
        float2 vc[4];

#pragma unroll
        for (int j = 0; j < 4; ++j) {
            int c = 4 * g + j;
            pl[j] = vin + base + (size_t)c * PLANE;
            vc[j] = pl[j][idx];
        }

#pragma unroll
        for (int j = 0; j < 4; ++j) {
            int c = 4 * g + j;
            if (FIRST) {
                a0j[j] = AB[2 * c];     b0j[j] = AB[32 + 2 * c];
                a1j[j] = AB[2 * c + 1]; b1j[j] = AB[32 + 2 * c + 1];
            }
            fy[j] = FIRST ? fmaf(a0j[j], vc[j].x, b0j[j]) : vc[j].x;
            fx[j] = FIRST ? fmaf(a1j[j], vc[j].y, b1j[j]) : vc[j].y;
            tap_setup((float)h + fy[j], (float)tx + fx[j], o[j], wt[j]);
        }

        float2 t[4][4];
#pragma unroll
        for (int j = 0; j < 4; ++j)
#pragma unroll
            for (int k = 0; k < 4; ++k) t[j][k] = pl[j][o[j][k]];

        float ny[4], nx[4];
        int   po[4][4];
        float pw[4][4];
#pragma unroll
        for (int j = 0; j < 4; ++j) {
            int c = 4 * g + j;
            float Sy = wt[j][0] * t[j][0].x + wt[j][1] * t[j][1].x
                     + wt[j][2] * t[j][2].x + wt[j][3] * t[j][3].x;
            float Sx = wt[j][0] * t[j][0].y + wt[j][1] * t[j][1].y
                     + wt[j][2] * t[j][2].y + wt[j][3] * t[j][3].y;
            if (FIRST) {
                float Ws = wt[j][0] + wt[j][1] + wt[j][2] + wt[j][3];
                ny[j] = fy[j] + fmaf(a0j[j], Sy, b0j[j] * Ws);
                nx[j] = fx[j] + fmaf(a1j[j], Sx, b1j[j] * Ws);
            } else {
                ny[j] = fy[j] + Sy;
                nx[j] = fx[j] + Sx;
            }
            if (!LAST)
                vout[base + (size_t)c * PLANE + idx] = make_float2(ny[j], nx[j]);
            tap_setup((float)h + ny[j], (float)tx + nx[j], po[j], pw[j]);
        }

#pragma unroll
        for (int j = 0; j < 4; ++j) {
            int c = 4 * g + j;
            const float* fp = f + base + (size_t)c * PLANE;
            mv[c] = pw[j][0] * fp[po[j][0]] + pw[j][1] * fp[po[j][1]]
                  + pw[j][2] * fp[po[j][2]] + pw[j][3] * fp[po[j][3]];
        }
    }

    float prev[IC];
    if (!FIRST) {
#pragma unroll
        for (int o = 0; o < IC; ++o)
            prev[o] = out[base + (size_t)o * PLANE + idx];
    }
#pragma unroll
    for (int o = 0; o < IC; ++o) {
        float acc = FIRST ? fb[o] : prev[o];
#pragma unroll
        for (int c = 0; c < IC; ++c)
            acc = fmaf(fw[(o * IC + c) * NSTEPS + step], mv[c], acc);
        out[base + (size_t)o * PLANE + idx] = acc;
    }
}

// ---------------------------------------------------------------------------
extern "C" void kernel_launch(void* const* d_in, const int* in_sizes, int n_in,
                              void* d_out, int out_size, void* d_ws,
                              size_t ws_size, hipStream_t stream) {
    const float* f      = (const float*)d_in[0];
    const float* vec_w  = (const float*)d_in[1];
    const float* vec_b  = (const float*)d_in[2];
    const float* gamma  = (const float*)d_in[3];
    const float* beta   = (const float*)d_in[4];
    const float* fuse_w = (const float*)d_in[5];
    const float* fuse_b = (const float*)d_in[6];
    float* out = (float*)d_out;

    float* ws = (float*)d_ws;
    const size_t bufElems = (size_t)NFIELDS * PLANE * 2;  // floats per buffer
    float2* buf0 = (float2*)ws;
    float2* buf1 = (float2*)(ws + bufElems);
    float*  wT   = ws + 2 * bufElems;
    float*  stats = wT + OCH * IC * 9;

    hipMemsetAsync(stats, 0, 64 * sizeof(float), stream);
    transpose_w_kernel<<<1, 512, 0, stream>>>(vec_w, wT);
    conv_kernel<<<2048, 256, 0, stream>>>(f, wT, vec_b, buf0);
    stats_kernel<<<NFIELDS * 16, 256, 0, stream>>>(buf0, stats);

    // host-side (capture-safe) occupancy gate for the cooperative path
    int blocksPerCU = 0;
    hipError_t qerr = hipOccupancyMaxActiveBlocksPerMultiprocessor(
        &blocksPerCU, (const void*)coop_steps_kernel, 256, 0);
    bool useCoop = (qerr == hipSuccess) && (blocksPerCU * NCU > 512);

    if (useCoop) {
        void* args[] = { (void*)&buf0, (void*)&buf1, (void*)&f, (void*)&stats,
                         (void*)&gamma, (void*)&beta, (void*)&fuse_w,
                         (void*)&fuse_b, (void*)&out };
        hipLaunchCooperativeKernel((const void*)coop_steps_kernel,
                                   dim3(512), dim3(256), args, 0, stream);
    } else {
        finalize_kernel<<<1, 64, 0, stream>>>(stats, gamma, beta, stats + 64);
        float2* vin = buf0;
        float2* vout = buf1;
        for (int s = 0; s < NSTEPS; ++s) {
            if (s == 0)
                step_kernel<true, false><<<BS * H, 256, 0, stream>>>(
                    vin, vout, f, stats + 64, fuse_w, fuse_b, out, s);
            else if (s < NSTEPS - 1)
                step_kernel<false, false><<<BS * H, 256, 0, stream>>>(
                    vin, vout, f, stats + 64, fuse_w, fuse_b, out, s);
            else
                step_kernel<false, true><<<BS * H, 256, 0, stream>>>(
                    vin, vout, f, stats + 64, fuse_w, fuse_b, out, s);
            float2* t = vin; vin = vout; vout = t;
        }
    }
}

// Round 5
// 693.135 us; speedup vs baseline: 1.2274x; 1.0022x over previous
//
#include <hip/hip_runtime.h>
#include <hip/hip_cooperative_groups.h>

namespace cg = cooperative_groups;

#define H 256
#define W 256
#define BS 8
#define IC 16          // in_ch (flow fields per batch; also out channels)
#define OCH 32         // conv output channels = 2*IC
#define NSTEPS 7
#define PLANE (H*W)            // 65536
#define NFIELDS (BS*IC)        // 128
#define BN_N (BS*PLANE)        // 524288 elements per BN channel
#define BN_EPS 1e-5f
#define NCU 256                // gfx950 CU count
#define COOP_GRID 1024         // 4 blocks/CU target

// ---------------------------------------------------------------------------
// K0: transpose vec_w [oc][ic][3][3] -> wT [ic*9+k][oc]  (contiguous over oc)
// ---------------------------------------------------------------------------
__global__ void transpose_w_kernel(const float* __restrict__ w,
                                   float* __restrict__ wT) {
    for (int idx = threadIdx.x; idx < OCH * IC * 9; idx += blockDim.x) {
        int oc  = idx / (IC * 9);
        int rem = idx - oc * (IC * 9);   // ic*9 + k
        wT[rem * OCH + oc] = w[idx];
    }
}

// ---------------------------------------------------------------------------
// K1: 3x3 conv (16->32) + bias. 16x16 tile, 1 px/thread, input staged in two
// 8-channel halves (10.9 KB LDS). launch_bounds(256,6): VGPR<=85, 6 blk/CU.
// ---------------------------------------------------------------------------
__global__ __launch_bounds__(256, 6) void conv_kernel(
    const float* __restrict__ f, const float* __restrict__ wT,
    const float* __restrict__ vec_b, float2* __restrict__ vec_out) {
    __shared__ float sf[8][18][19];    // row padded to 19 for bank spread

    int blk = blockIdx.x;              // 8 * 256 = 2048
    int b   = blk >> 8;
    int rem = blk & 255;
    int ty0 = (rem >> 4) * 16;
    int tx0 = (rem & 15) * 16;
    int tid = threadIdx.x;
    int ty  = tid >> 4, tx = tid & 15;

    float acc[OCH];
#pragma unroll
    for (int oc = 0; oc < OCH; ++oc) acc[oc] = vec_b[oc];

    for (int half = 0; half < 2; ++half) {
        if (half) __syncthreads();     // protect LDS overwrite
        for (int idx = tid; idx < 8 * 18 * 18; idx += 256) {
            int ic = idx / 324;
            int r2 = idx - ic * 324;
            int r  = r2 / 18;
            int cc = r2 - r * 18;
            int gy = ty0 - 1 + r, gx = tx0 - 1 + cc;
            float v = 0.f;
            if (gy >= 0 && gy < H && gx >= 0 && gx < W)
                v = f[((size_t)(b * IC + half * 8 + ic) * H + gy) * W + gx];
            sf[ic][r][cc] = v;
        }
        __syncthreads();

#pragma unroll 2
        for (int ic = 0; ic < 8; ++ic) {
#pragma unroll
            for (int k = 0; k < 9; ++k) {
                int ky = k / 3, kx = k - ky * 3;
                float fv = sf[ic][ty + ky][tx + kx];
                const float* wrow = wT + ((half * 8 + ic) * 9 + k) * OCH;
#pragma unroll
                for (int oc = 0; oc < OCH; ++oc)
                    acc[oc] = fmaf(fv, wrow[oc], acc[oc]);
            }
        }
    }

    int y = ty0 + ty, x = tx0 + tx;
#pragma unroll
    for (int c = 0; c < IC; ++c) {
        vec_out[(size_t)(b * IC + c) * PLANE + y * W + x] =
            make_float2(acc[2 * c], acc[2 * c + 1]);
    }
}

// ---------------------------------------------------------------------------
// K2: per-channel sum / sumsq over the interleaved conv output.
// ---------------------------------------------------------------------------
__global__ __launch_bounds__(256) void stats_kernel(
    const float2* __restrict__ vec, float* __restrict__ stats) {
    int blk   = blockIdx.x;            // NFIELDS*16 = 2048
    int n     = blk >> 4;
    int chunk = blk & 15;
    const float4* p = (const float4*)(vec + (size_t)n * PLANE) + chunk * 2048;
    int tid = threadIdx.x;

    float s0 = 0.f, s1 = 0.f, q0 = 0.f, q1 = 0.f;
#pragma unroll 4
    for (int i = tid; i < 2048; i += 256) {
        float4 v = p[i];
        s0 += v.x + v.z; s1 += v.y + v.w;
        q0 = fmaf(v.x, v.x, fmaf(v.z, v.z, q0));
        q1 = fmaf(v.y, v.y, fmaf(v.w, v.w, q1));
    }
#pragma unroll
    for (int off = 32; off > 0; off >>= 1) {
        s0 += __shfl_down(s0, off, 64);
        s1 += __shfl_down(s1, off, 64);
        q0 += __shfl_down(q0, off, 64);
        q1 += __shfl_down(q1, off, 64);
    }
    __shared__ float red[4][4];
    int wave = tid >> 6, lane = tid & 63;
    if (lane == 0) {
        red[wave][0] = s0; red[wave][1] = s1;
        red[wave][2] = q0; red[wave][3] = q1;
    }
    __syncthreads();
    if (tid == 0) {
        float t0 = 0.f, t1 = 0.f, t2 = 0.f, t3 = 0.f;
#pragma unroll
        for (int wv = 0; wv < 4; ++wv) {
            t0 += red[wv][0]; t1 += red[wv][1];
            t2 += red[wv][2]; t3 += red[wv][3];
        }
        int ch0 = 2 * (n & 15);
        atomicAdd(stats + ch0,          t0);
        atomicAdd(stats + ch0 + 1,      t1);
        atomicAdd(stats + 32 + ch0,     t2);
        atomicAdd(stats + 32 + ch0 + 1, t3);
    }
}

// ---------------------------------------------------------------------------
// K3: fold BN + 1/128 scale into per-channel affine (fallback path).
// ---------------------------------------------------------------------------
__global__ void finalize_kernel(const float* __restrict__ stats,
                                const float* __restrict__ gamma,
                                const float* __restrict__ beta,
                                float* __restrict__ AB) {
    int ch = threadIdx.x;
    if (ch < 2 * IC) {
        const float invN = 1.f / (float)BN_N;
        float mean = stats[ch] * invN;
        float var  = stats[32 + ch] * invN - mean * mean;
        float rs   = rsqrtf(var + BN_EPS);
        float a    = gamma[ch] * rs;
        AB[ch]      = a * (1.f / 128.f);
        AB[32 + ch] = (beta[ch] - a * mean) * (1.f / 128.f);
    }
}

// ---------------------------------------------------------------------------
// bilinear tap setup: clamped offsets + validity-masked weights
// ---------------------------------------------------------------------------
__device__ __forceinline__ void tap_setup(float py, float px,
                                          int* o, float* wt) {
    float ffy = floorf(py), ffx = floorf(px);
    int y0 = (int)ffy, x0 = (int)ffx;
    float wy1 = py - ffy, wy0 = 1.f - wy1;
    float wx1 = px - ffx, wx0 = 1.f - wx1;
    bool vy0 = (unsigned)y0 < (unsigned)H, vy1 = (unsigned)(y0 + 1) < (unsigned)H;
    bool vx0 = (unsigned)x0 < (unsigned)W, vx1 = (unsigned)(x0 + 1) < (unsigned)W;
    int yc0 = min(max(y0, 0), H - 1), yc1 = min(max(y0 + 1, 0), H - 1);
    int xc0 = min(max(x0, 0), W - 1), xc1 = min(max(x0 + 1, 0), W - 1);
    o[0] = yc0 * W + xc0; o[1] = yc0 * W + xc1;
    o[2] = yc1 * W + xc0; o[3] = yc1 * W + xc1;
    wt[0] = (vy0 && vx0) ? wy0 * wx0 : 0.f;
    wt[1] = (vy0 && vx1) ? wy0 * wx1 : 0.f;
    wt[2] = (vy1 && vx0) ? wy1 * wx0 : 0.f;
    wt[3] = (vy1 && vx1) ? wy1 * wx1 : 0.f;
}

// ---------------------------------------------------------------------------
// K4-coop: all 7 steps in one cooperative kernel. 1024 blocks x 256 threads;
// block owns (b, 2 rows), thread owns 2 pixels (4 gather streams = 2ch x 2px).
// Output accumulator stays in registers across all steps (no out RMW).
// launch_bounds(256,4): VGPR<=128; expected actual ~70 -> 6-7 blocks/CU
// capacity, strict slack over the 1024-block grid (4/CU resident).
// ---------------------------------------------------------------------------
__global__ __launch_bounds__(256, 4) void coop_steps_kernel(
    float2* __restrict__ buf0, float2* __restrict__ buf1,
    const float* __restrict__ f, const float* __restrict__ stats,
    const float* __restrict__ gamma, const float* __restrict__ beta,
    const float* __restrict__ fw, const float* __restrict__ fb,
    float* __restrict__ out) {
    cg::grid_group grid = cg::this_grid();

    __shared__ float sAB[64];     // A[32] (gain/128), B[32] (bias/128)
    __shared__ float sFW[256];    // fw[:,:,s] for the current step

    int tid = threadIdx.x;
    if (tid < 32) {
        const float invN = 1.f / (float)BN_N;
        float mean = stats[tid] * invN;
        float var  = stats[32 + tid] * invN - mean * mean;
        float a    = gamma[tid] * rsqrtf(var + BN_EPS);
        sAB[tid]      = a * (1.f / 128.f);
        sAB[32 + tid] = (beta[tid] - a * mean) * (1.f / 128.f);
    }

    int blk = blockIdx.x;          // 1024
    int b   = blk >> 7;            // 128 blocks per batch
    int h0  = (blk & 127) << 1;    // rows h0, h0+1
    int tx  = tid;
    const size_t base = (size_t)b * IC * PLANE;
    int idx0 = h0 * W + tx, idx1 = idx0 + W;

    float acc[2][IC];
#pragma unroll
    for (int o = 0; o < IC; ++o) { acc[0][o] = fb[o]; acc[1][o] = fb[o]; }

    for (int s = 0; s < NSTEPS; ++s) {
        const bool first = (s == 0), last = (s == NSTEPS - 1);
        const float2* __restrict__ vin  = (s & 1) ? buf1 : buf0;
        float2* __restrict__       vout = (s & 1) ? buf0 : buf1;

        sFW[tid] = fw[tid * NSTEPS + s];   // tid = o*16+c
        __syncthreads();

        for (int cp = 0; cp < 8; ++cp) {   // channel pairs: c = 2cp, 2cp+1
            const float2* pl[2];
            float2 vc[4];                  // stream q = 2*j + p
#pragma unroll
            for (int j = 0; j < 2; ++j) {
                int c = 2 * cp + j;
                pl[j] = vin + base + (size_t)c * PLANE;
                vc[2 * j + 0] = pl[j][idx0];
                vc[2 * j + 1] = pl[j][idx1];
            }

            float fy[4], fx[4];
            int   o[4][4];
            float wt[4][4];
#pragma unroll
            for (int q = 0; q < 4; ++q) {
                int j = q >> 1, p = q & 1, c = 2 * cp + j;
                if (first) {
                    fy[q] = fmaf(sAB[2 * c],     vc[q].x, sAB[32 + 2 * c]);
                    fx[q] = fmaf(sAB[2 * c + 1], vc[q].y, sAB[32 + 2 * c + 1]);
                } else {
                    fy[q] = vc[q].x;
                    fx[q] = vc[q].y;
                }
                tap_setup((float)(h0 + p) + fy[q], (float)tx + fx[q],
                          o[q], wt[q]);
            }

            float2 t[4][4];
#pragma unroll
            for (int q = 0; q < 4; ++q)
#pragma unroll
                for (int k = 0; k < 4; ++k)
                    t[q][k] = pl[q >> 1][o[q][k]];

            float ny[4], nx[4];
            int   po[4][4];
            float pw[4][4];
#pragma unroll
            for (int q = 0; q < 4; ++q) {
                int j = q >> 1, p = q & 1, c = 2 * cp + j;
                float Sy = wt[q][0] * t[q][0].x + wt[q][1] * t[q][1].x
                         + wt[q][2] * t[q][2].x + wt[q][3] * t[q][3].x;
                float Sx = wt[q][0] * t[q][0].y + wt[q][1] * t[q][1].y
                         + wt[q][2] * t[q][2].y + wt[q][3] * t[q][3].y;
                if (first) {
                    float Ws = wt[q][0] + wt[q][1] + wt[q][2] + wt[q][3];
                    ny[q] = fy[q] + fmaf(sAB[2 * c],     Sy, sAB[32 + 2 * c] * Ws);
                    nx[q] = fx[q] + fmaf(sAB[2 * c + 1], Sx, sAB[32 + 2 * c + 1] * Ws);
                } else {
                    ny[q] = fy[q] + Sy;
                    nx[q] = fx[q] + Sx;
                }
                if (!last)
                    vout[base + (size_t)c * PLANE + (p ? idx1 : idx0)] =
                        make_float2(ny[q], nx[q]);
                tap_setup((float)(h0 + p) + ny[q], (float)tx + nx[q],
                          po[q], pw[q]);
            }

            float m[4];
#pragma unroll
            for (int q = 0; q < 4; ++q) {
                int c = 2 * cp + (q >> 1);
                const float* fp = f + base + (size_t)c * PLANE;
                m[q] = pw[q][0] * fp[po[q][0]] + pw[q][1] * fp[po[q][1]]
                     + pw[q][2] * fp[po[q][2]] + pw[q][3] * fp[po[q][3]];
            }

#pragma unroll
            for (int q = 0; q < 4; ++q) {
                int c = 2 * cp + (q >> 1), p = q & 1;
#pragma unroll
                for (int oo = 0; oo < IC; ++oo)
                    acc[p][oo] = fmaf(sFW[oo * IC + c], m[q], acc[p][oo]);
            }
        }

        if (!last) {
            __threadfence();
            grid.sync();
            __threadfence();
        }
    }

#pragma unroll
    for (int oo = 0; oo < IC; ++oo) {
        out[base + (size_t)oo * PLANE + idx0] = acc[0][oo];
        out[base + (size_t)oo * PLANE + idx1] = acc[1][oo];
    }
}

// ---------------------------------------------------------------------------
// K4-fallback: one step per launch (validated in R2), out RMW per step.
// ---------------------------------------------------------------------------
template <bool FIRST, bool LAST>
__global__ __launch_bounds__(256) void step_kernel(
    const float2* __restrict__ vin, float2* __restrict__ vout,
    const float* __restrict__ f, const float* __restrict__ AB,
    const float* __restrict__ fw, const float* __restrict__ fb,
    float* __restrict__ out, int step) {
    int blk = blockIdx.x;             // BS*H = 2048
    int b   = blk >> 8;
    int h   = blk & (H - 1);
    int tx  = threadIdx.x;
    int idx = h * W + tx;
    const size_t base = (size_t)b * IC * PLANE;

    float mv[IC];

#pragma unroll 2
    for (int g = 0; g < 4; ++g) {
        float a0j[4], b0j[4], a1j[4], b1j[4];
        float fy[4], fx[4];
        int   o[4][4];
        float wt[4][4];
        const float2* pl[4];
        float2 vc[4];

#pragma unroll
        for (int j = 0; j < 4; ++j) {
            int c = 4 * g + j;
            pl[j] = vin + base + (size_t)c * PLANE;
            vc[j] = pl[j][idx];
        }

#pragma unroll
        for (int j = 0; j < 4; ++j) {
            int c = 4 * g + j;
            if (FIRST) {
                a0j[j] = AB[2 * c];     b0j[j] = AB[32 + 2 * c];
                a1j[j] = AB[2 * c + 1]; b1j[j] = AB[32 + 2 * c + 1];
            }
            fy[j] = FIRST ? fmaf(a0j[j], vc[j].x, b0j[j]) : vc[j].x;
            fx[j] = FIRST ? fmaf(a1j[j], vc[j].y, b1j[j]) : vc[j].y;
            tap_setup((float)h + fy[j], (float)tx + fx[j], o[j], wt[j]);
        }

        float2 t[4][4];
#pragma unroll
        for (int j = 0; j < 4; ++j)
#pragma unroll
            for (int k = 0; k < 4; ++k) t[j][k] = pl[j][o[j][k]];

        float ny[4], nx[4];
        int   po[4][4];
        float pw[4][4];
#pragma unroll
        for (int j = 0; j < 4; ++j) {
            int c = 4 * g + j;
            float Sy = wt[j][0] * t[j][0].x + wt[j][1] * t[j][1].x
                     + wt[j][2] * t[j][2].x + wt[j][3] * t[j][3].x;
            float Sx = wt[j][0] * t[j][0].y + wt[j][1] * t[j][1].y
                     + wt[j][2] * t[j][2].y + wt[j][3] * t[j][3].y;
            if (FIRST) {
                float Ws = wt[j][0] + wt[j][1] + wt[j][2] + wt[j][3];
                ny[j] = fy[j] + fmaf(a0j[j], Sy, b0j[j] * Ws);
                nx[j] = fx[j] + fmaf(a1j[j], Sx, b1j[j] * Ws);
            } else {
                ny[j] = fy[j] + Sy;
                nx[j] = fx[j] + Sx;
            }
            if (!LAST)
                vout[base + (size_t)c * PLANE + idx] = make_float2(ny[j], nx[j]);
            tap_setup((float)h + ny[j], (float)tx + nx[j], po[j], pw[j]);
        }

#pragma unroll
        for (int j = 0; j < 4; ++j) {
            int c = 4 * g + j;
            const float* fp = f + base + (size_t)c * PLANE;
            mv[c] = pw[j][0] * fp[po[j][0]] + pw[j][1] * fp[po[j][1]]
                  + pw[j][2] * fp[po[j][2]] + pw[j][3] * fp[po[j][3]];
        }
    }

    float prev[IC];
    if (!FIRST) {
#pragma unroll
        for (int o = 0; o < IC; ++o)
            prev[o] = out[base + (size_t)o * PLANE + idx];
    }
#pragma unroll
    for (int o = 0; o < IC; ++o) {
        float acc = FIRST ? fb[o] : prev[o];
#pragma unroll
        for (int c = 0; c < IC; ++c)
            acc = fmaf(fw[(o * IC + c) * NSTEPS + step], mv[c], acc);
        out[base + (size_t)o * PLANE + idx] = acc;
    }
}

// ---------------------------------------------------------------------------
extern "C" void kernel_launch(void* const* d_in, const int* in_sizes, int n_in,
                              void* d_out, int out_size, void* d_ws,
                              size_t ws_size, hipStream_t stream) {
    const float* f      = (const float*)d_in[0];
    const float* vec_w  = (const float*)d_in[1];
    const float* vec_b  = (const float*)d_in[2];
    const float* gamma  = (const float*)d_in[3];
    const float* beta   = (const float*)d_in[4];
    const float* fuse_w = (const float*)d_in[5];
    const float* fuse_b = (const float*)d_in[6];
    float* out = (float*)d_out;

    float* ws = (float*)d_ws;
    const size_t bufElems = (size_t)NFIELDS * PLANE * 2;  // floats per buffer
    float2* buf0 = (float2*)ws;
    float2* buf1 = (float2*)(ws + bufElems);
    float*  wT   = ws + 2 * bufElems;
    float*  stats = wT + OCH * IC * 9;

    hipMemsetAsync(stats, 0, 64 * sizeof(float), stream);
    transpose_w_kernel<<<1, 512, 0, stream>>>(vec_w, wT);
    conv_kernel<<<2048, 256, 0, stream>>>(f, wT, vec_b, buf0);
    stats_kernel<<<NFIELDS * 16, 256, 0, stream>>>(buf0, stats);

    // host-side (capture-safe) occupancy gate for the cooperative path
    int blocksPerCU = 0;
    hipError_t qerr = hipOccupancyMaxActiveBlocksPerMultiprocessor(
        &blocksPerCU, (const void*)coop_steps_kernel, 256, 0);
    bool useCoop = (qerr == hipSuccess) && (blocksPerCU * NCU >= COOP_GRID);

    if (useCoop) {
        void* args[] = { (void*)&buf0, (void*)&buf1, (void*)&f, (void*)&stats,
                         (void*)&gamma, (void*)&beta, (void*)&fuse_w,
                         (void*)&fuse_b, (void*)&out };
        hipLaunchCooperativeKernel((const void*)coop_steps_kernel,
                                   dim3(COOP_GRID), dim3(256), args, 0, stream);
    } else {
        finalize_kernel<<<1, 64, 0, stream>>>(stats, gamma, beta, stats + 64);
        float2* vin = buf0;
        float2* vout = buf1;
        for (int s = 0; s < NSTEPS; ++s) {
            if (s == 0)
                step_kernel<true, false><<<BS * H, 256, 0, stream>>>(
                    vin, vout, f, stats + 64, fuse_w, fuse_b, out, s);
            else if (s < NSTEPS - 1)
                step_kernel<false, false><<<BS * H, 256, 0, stream>>>(
                    vin, vout, f, stats + 64, fuse_w, fuse_b, out, s);
            else
                step_kernel<false, true><<<BS * H, 256, 0, stream>>>(
                    vin, vout, f, stats + 64, fuse_w, fuse_b, out, s);
            float2* t = vin; vin = vout; vout = t;
        }
    }
}

// Round 6
// 663.472 us; speedup vs baseline: 1.2822x; 1.0447x over previous
//
#include <hip/hip_runtime.h>
#include <hip/hip_fp16.h>

#define H 256
#define W 256
#define BS 8
#define IC 16          // in_ch (flow fields per batch; also out channels)
#define OCH 32         // conv output channels = 2*IC
#define NSTEPS 7
#define PLANE (H*W)            // 65536
#define NFIELDS (BS*IC)        // 128
#define BN_N (BS*PLANE)        // 524288 elements per BN channel
#define BN_EPS 1e-5f

// ---------------------------------------------------------------------------
// K0: transpose vec_w [oc][ic][3][3] -> wT [ic*9+k][oc]
// ---------------------------------------------------------------------------
__global__ void transpose_w_kernel(const float* __restrict__ w,
                                   float* __restrict__ wT) {
    for (int idx = threadIdx.x; idx < OCH * IC * 9; idx += blockDim.x) {
        int oc  = idx / (IC * 9);
        int rem = idx - oc * (IC * 9);
        wT[rem * OCH + oc] = w[idx];
    }
}

// ---------------------------------------------------------------------------
// K1: 3x3 conv (16->32) + bias -> half2 flow fields; also emits fp16 copy of
// f for the later gather passes. 16x16 tile, two 8-channel staging halves.
// ---------------------------------------------------------------------------
__global__ __launch_bounds__(256, 6) void conv_kernel(
    const float* __restrict__ f, const float* __restrict__ wT,
    const float* __restrict__ vec_b, __half2* __restrict__ vec_out,
    __half* __restrict__ f16c) {
    __shared__ float sf[8][18][19];

    int blk = blockIdx.x;              // 2048
    int b   = blk >> 8;
    int rem = blk & 255;
    int ty0 = (rem >> 4) * 16;
    int tx0 = (rem & 15) * 16;
    int tid = threadIdx.x;
    int ty  = tid >> 4, tx = tid & 15;
    int y = ty0 + ty, x = tx0 + tx;

    float acc[OCH];
#pragma unroll
    for (int oc = 0; oc < OCH; ++oc) acc[oc] = vec_b[oc];

    for (int half = 0; half < 2; ++half) {
        if (half) __syncthreads();
        for (int idx = tid; idx < 8 * 18 * 18; idx += 256) {
            int ic = idx / 324;
            int r2 = idx - ic * 324;
            int r  = r2 / 18;
            int cc = r2 - r * 18;
            int gy = ty0 - 1 + r, gx = tx0 - 1 + cc;
            float v = 0.f;
            if (gy >= 0 && gy < H && gx >= 0 && gx < W)
                v = f[((size_t)(b * IC + half * 8 + ic) * H + gy) * W + gx];
            sf[ic][r][cc] = v;
        }
        __syncthreads();

#pragma unroll 2
        for (int ic = 0; ic < 8; ++ic) {
            // fp16 copy of f (center pixel) for gather passes
            f16c[(size_t)(b * IC + half * 8 + ic) * PLANE + y * W + x] =
                __float2half(sf[ic][ty + 1][tx + 1]);
#pragma unroll
            for (int k = 0; k < 9; ++k) {
                int ky = k / 3, kx = k - ky * 3;
                float fv = sf[ic][ty + ky][tx + kx];
                const float* wrow = wT + ((half * 8 + ic) * 9 + k) * OCH;
#pragma unroll
                for (int oc = 0; oc < OCH; ++oc)
                    acc[oc] = fmaf(fv, wrow[oc], acc[oc]);
            }
        }
    }

#pragma unroll
    for (int c = 0; c < IC; ++c) {
        vec_out[(size_t)(b * IC + c) * PLANE + y * W + x] =
            __float22half2_rn(make_float2(acc[2 * c], acc[2 * c + 1]));
    }
}

// ---------------------------------------------------------------------------
// K2: per-channel sum / sumsq over the half2 conv output.
// ---------------------------------------------------------------------------
__global__ __launch_bounds__(256) void stats_kernel(
    const __half2* __restrict__ vec, float* __restrict__ stats) {
    int blk   = blockIdx.x;            // NFIELDS*16 = 2048
    int n     = blk >> 4;
    int chunk = blk & 15;
    const __half2* p = vec + (size_t)n * PLANE + chunk * 4096;
    int tid = threadIdx.x;

    float s0 = 0.f, s1 = 0.f, q0 = 0.f, q1 = 0.f;
#pragma unroll 4
    for (int i = tid; i < 4096; i += 256) {
        float2 v = __half22float2(p[i]);
        s0 += v.x; s1 += v.y;
        q0 = fmaf(v.x, v.x, q0);
        q1 = fmaf(v.y, v.y, q1);
    }
#pragma unroll
    for (int off = 32; off > 0; off >>= 1) {
        s0 += __shfl_down(s0, off, 64);
        s1 += __shfl_down(s1, off, 64);
        q0 += __shfl_down(q0, off, 64);
        q1 += __shfl_down(q1, off, 64);
    }
    __shared__ float red[4][4];
    int wave = tid >> 6, lane = tid & 63;
    if (lane == 0) {
        red[wave][0] = s0; red[wave][1] = s1;
        red[wave][2] = q0; red[wave][3] = q1;
    }
    __syncthreads();
    if (tid == 0) {
        float t0 = 0.f, t1 = 0.f, t2 = 0.f, t3 = 0.f;
#pragma unroll
        for (int wv = 0; wv < 4; ++wv) {
            t0 += red[wv][0]; t1 += red[wv][1];
            t2 += red[wv][2]; t3 += red[wv][3];
        }
        int ch0 = 2 * (n & 15);
        atomicAdd(stats + ch0,          t0);
        atomicAdd(stats + ch0 + 1,      t1);
        atomicAdd(stats + 32 + ch0,     t2);
        atomicAdd(stats + 32 + ch0 + 1, t3);
    }
}

// ---------------------------------------------------------------------------
// K3: fold BN + 1/128 scale into per-channel affine.
// ---------------------------------------------------------------------------
__global__ void finalize_kernel(const float* __restrict__ stats,
                                const float* __restrict__ gamma,
                                const float* __restrict__ beta,
                                float* __restrict__ AB) {
    int ch = threadIdx.x;
    if (ch < 2 * IC) {
        const float invN = 1.f / (float)BN_N;
        float mean = stats[ch] * invN;
        float var  = stats[32 + ch] * invN - mean * mean;
        float rs   = rsqrtf(var + BN_EPS);
        float a    = gamma[ch] * rs;
        AB[ch]      = a * (1.f / 128.f);
        AB[32 + ch] = (beta[ch] - a * mean) * (1.f / 128.f);
    }
}

// ---------------------------------------------------------------------------
// bilinear tap setup: clamped offsets + validity-masked weights
// ---------------------------------------------------------------------------
__device__ __forceinline__ void tap_setup(float py, float px,
                                          int* o, float* wt) {
    float ffy = floorf(py), ffx = floorf(px);
    int y0 = (int)ffy, x0 = (int)ffx;
    float wy1 = py - ffy, wy0 = 1.f - wy1;
    float wx1 = px - ffx, wx0 = 1.f - wx1;
    bool vy0 = (unsigned)y0 < (unsigned)H, vy1 = (unsigned)(y0 + 1) < (unsigned)H;
    bool vx0 = (unsigned)x0 < (unsigned)W, vx1 = (unsigned)(x0 + 1) < (unsigned)W;
    int yc0 = min(max(y0, 0), H - 1), yc1 = min(max(y0 + 1, 0), H - 1);
    int xc0 = min(max(x0, 0), W - 1), xc1 = min(max(x0 + 1, 0), W - 1);
    o[0] = yc0 * W + xc0; o[1] = yc0 * W + xc1;
    o[2] = yc1 * W + xc0; o[3] = yc1 * W + xc1;
    wt[0] = (vy0 && vx0) ? wy0 * wx0 : 0.f;
    wt[1] = (vy0 && vx1) ? wy0 * wx1 : 0.f;
    wt[2] = (vy1 && vx0) ? wy1 * wx0 : 0.f;
    wt[3] = (vy1 && vx1) ? wy1 * wx1 : 0.f;
}

// ---------------------------------------------------------------------------
// K4: one scaling-and-squaring step on half2 deforms + fused f16 f-warp.
// MAPS: steps 0..5 write fp16 maps to ws; LAST fuses all 7 maps -> out.
// !MAPS fallback: f32 out RMW per step (R2 semantics).
// Grid 2048 (b,row), 256 threads (col), 4-channel gather groups.
// ---------------------------------------------------------------------------
template <bool FIRST, bool LAST, bool MAPS>
__global__ __launch_bounds__(256) void step_kernel(
    const __half2* __restrict__ vin, __half2* __restrict__ vout,
    const __half* __restrict__ f16c, const float* __restrict__ AB,
    const float* __restrict__ fw, const float* __restrict__ fb,
    __half* __restrict__ maps, float* __restrict__ out, int step) {
    __shared__ float sFW[IC * IC * NSTEPS];   // only used when LAST&&MAPS

    if (LAST && MAPS) {
        for (int i = threadIdx.x; i < IC * IC * NSTEPS; i += 256)
            sFW[i] = fw[i];
        __syncthreads();
    }

    int blk = blockIdx.x;             // BS*H = 2048
    int b   = blk >> 8;
    int h   = blk & (H - 1);
    int tx  = threadIdx.x;
    int idx = h * W + tx;
    const size_t base = (size_t)b * IC * PLANE;

    float mv[IC];

#pragma unroll 2
    for (int g = 0; g < 4; ++g) {
        float a0j[4], b0j[4], a1j[4], b1j[4];
        float fy[4], fx[4];
        int   o[4][4];
        float wt[4][4];
        const __half2* pl[4];
        float2 vc[4];

#pragma unroll
        for (int j = 0; j < 4; ++j) {
            int c = 4 * g + j;
            pl[j] = vin + base + (size_t)c * PLANE;
            vc[j] = __half22float2(pl[j][idx]);
        }

#pragma unroll
        for (int j = 0; j < 4; ++j) {
            int c = 4 * g + j;
            if (FIRST) {
                a0j[j] = AB[2 * c];     b0j[j] = AB[32 + 2 * c];
                a1j[j] = AB[2 * c + 1]; b1j[j] = AB[32 + 2 * c + 1];
            }
            fy[j] = FIRST ? fmaf(a0j[j], vc[j].x, b0j[j]) : vc[j].x;
            fx[j] = FIRST ? fmaf(a1j[j], vc[j].y, b1j[j]) : vc[j].y;
            tap_setup((float)h + fy[j], (float)tx + fx[j], o[j], wt[j]);
        }

        float2 t[4][4];
#pragma unroll
        for (int j = 0; j < 4; ++j)
#pragma unroll
            for (int k = 0; k < 4; ++k)
                t[j][k] = __half22float2(pl[j][o[j][k]]);

        float ny[4], nx[4];
        int   po[4][4];
        float pw[4][4];
#pragma unroll
        for (int j = 0; j < 4; ++j) {
            int c = 4 * g + j;
            float Sy = wt[j][0] * t[j][0].x + wt[j][1] * t[j][1].x
                     + wt[j][2] * t[j][2].x + wt[j][3] * t[j][3].x;
            float Sx = wt[j][0] * t[j][0].y + wt[j][1] * t[j][1].y
                     + wt[j][2] * t[j][2].y + wt[j][3] * t[j][3].y;
            if (FIRST) {
                float Ws = wt[j][0] + wt[j][1] + wt[j][2] + wt[j][3];
                ny[j] = fy[j] + fmaf(a0j[j], Sy, b0j[j] * Ws);
                nx[j] = fx[j] + fmaf(a1j[j], Sx, b1j[j] * Ws);
            } else {
                ny[j] = fy[j] + Sy;
                nx[j] = fx[j] + Sx;
            }
            if (!LAST)
                vout[base + (size_t)c * PLANE + idx] =
                    __float22half2_rn(make_float2(ny[j], nx[j]));
            tap_setup((float)h + ny[j], (float)tx + nx[j], po[j], pw[j]);
        }

#pragma unroll
        for (int j = 0; j < 4; ++j) {
            int c = 4 * g + j;
            const __half* fp = f16c + base + (size_t)c * PLANE;
            mv[c] = pw[j][0] * __half2float(fp[po[j][0]])
                  + pw[j][1] * __half2float(fp[po[j][1]])
                  + pw[j][2] * __half2float(fp[po[j][2]])
                  + pw[j][3] * __half2float(fp[po[j][3]]);
        }
    }

    if (MAPS) {
        if (!LAST) {
            // write this step's warped map (fp16)
#pragma unroll
            for (int c = 0; c < IC; ++c)
                maps[((size_t)step * NFIELDS + b * IC + c) * PLANE + idx] =
                    __float2half(mv[c]);
        } else {
            // fuse: out_o = fb_o + sum_s sum_c fw[o,c,s] * M[s,c]
            float acc[IC];
#pragma unroll
            for (int oo = 0; oo < IC; ++oo) acc[oo] = fb[oo];
#pragma unroll 1
            for (int s = 0; s < NSTEPS - 1; ++s) {
                float ms[IC];
#pragma unroll
                for (int c = 0; c < IC; ++c)
                    ms[c] = __half2float(
                        maps[((size_t)s * NFIELDS + b * IC + c) * PLANE + idx]);
#pragma unroll
                for (int oo = 0; oo < IC; ++oo)
#pragma unroll
                    for (int c = 0; c < IC; ++c)
                        acc[oo] = fmaf(sFW[(oo * IC + c) * NSTEPS + s],
                                       ms[c], acc[oo]);
            }
#pragma unroll
            for (int oo = 0; oo < IC; ++oo) {
#pragma unroll
                for (int c = 0; c < IC; ++c)
                    acc[oo] = fmaf(sFW[(oo * IC + c) * NSTEPS + NSTEPS - 1],
                                   mv[c], acc[oo]);
                out[base + (size_t)oo * PLANE + idx] = acc[oo];
            }
        }
    } else {
        // fallback: f32 out read-modify-write with this step's fw column
        float prev[IC];
        if (!FIRST) {
#pragma unroll
            for (int o2 = 0; o2 < IC; ++o2)
                prev[o2] = out[base + (size_t)o2 * PLANE + idx];
        }
#pragma unroll
        for (int o2 = 0; o2 < IC; ++o2) {
            float a = FIRST ? fb[o2] : prev[o2];
#pragma unroll
            for (int c = 0; c < IC; ++c)
                a = fmaf(fw[(o2 * IC + c) * NSTEPS + step], mv[c], a);
            out[base + (size_t)o2 * PLANE + idx] = a;
        }
    }
}

// ---------------------------------------------------------------------------
extern "C" void kernel_launch(void* const* d_in, const int* in_sizes, int n_in,
                              void* d_out, int out_size, void* d_ws,
                              size_t ws_size, hipStream_t stream) {
    const float* f      = (const float*)d_in[0];
    const float* vec_w  = (const float*)d_in[1];
    const float* vec_b  = (const float*)d_in[2];
    const float* gamma  = (const float*)d_in[3];
    const float* beta   = (const float*)d_in[4];
    const float* fuse_w = (const float*)d_in[5];
    const float* fuse_b = (const float*)d_in[6];
    float* out = (float*)d_out;

    // ws layout (bytes):
    //   buf0:  NFIELDS*PLANE half2            = 33.55 MB
    //   buf1:  NFIELDS*PLANE half2            = 33.55 MB
    //   f16c:  NFIELDS*PLANE half             = 16.78 MB
    //   maps:  6*NFIELDS*PLANE half           = 100.7 MB   (MAPS path)
    //   wT, stats/AB: small
    char* ws = (char*)d_ws;
    const size_t fieldBytes2 = (size_t)NFIELDS * PLANE * sizeof(__half2);
    const size_t fieldBytes1 = (size_t)NFIELDS * PLANE * sizeof(__half);
    __half2* buf0 = (__half2*)ws;
    __half2* buf1 = (__half2*)(ws + fieldBytes2);
    __half*  f16c = (__half*)(ws + 2 * fieldBytes2);
    __half*  maps = (__half*)(ws + 2 * fieldBytes2 + fieldBytes1);
    char*    tail = ws + 2 * fieldBytes2 + fieldBytes1 + 6 * fieldBytes1;
    float*   wT   = (float*)tail;
    float*   stats = wT + OCH * IC * 9;
    size_t needed = (size_t)(tail - ws) + (OCH * IC * 9 + 128) * sizeof(float);
    bool useMaps = ws_size >= needed;
    if (!useMaps) {
        // compact layout without maps
        wT    = (float*)(ws + 2 * fieldBytes2 + fieldBytes1);
        stats = wT + OCH * IC * 9;
    }

    hipMemsetAsync(stats, 0, 64 * sizeof(float), stream);
    transpose_w_kernel<<<1, 512, 0, stream>>>(vec_w, wT);
    conv_kernel<<<2048, 256, 0, stream>>>(f, wT, vec_b, buf0, f16c);
    stats_kernel<<<NFIELDS * 16, 256, 0, stream>>>(buf0, stats);
    finalize_kernel<<<1, 64, 0, stream>>>(stats, gamma, beta, stats + 64);
    float* AB = stats + 64;

    __half2* vin = buf0;
    __half2* vout = buf1;
    for (int s = 0; s < NSTEPS; ++s) {
        if (useMaps) {
            if (s == 0)
                step_kernel<true, false, true><<<2048, 256, 0, stream>>>(
                    vin, vout, f16c, AB, fuse_w, fuse_b, maps, out, s);
            else if (s < NSTEPS - 1)
                step_kernel<false, false, true><<<2048, 256, 0, stream>>>(
                    vin, vout, f16c, AB, fuse_w, fuse_b, maps, out, s);
            else
                step_kernel<false, true, true><<<2048, 256, 0, stream>>>(
                    vin, vout, f16c, AB, fuse_w, fuse_b, maps, out, s);
        } else {
            if (s == 0)
                step_kernel<true, false, false><<<2048, 256, 0, stream>>>(
                    vin, vout, f16c, AB, fuse_w, fuse_b, maps, out, s);
            else if (s < NSTEPS - 1)
                step_kernel<false, false, false><<<2048, 256, 0, stream>>>(
                    vin, vout, f16c, AB, fuse_w, fuse_b, maps, out, s);
            else
                step_kernel<false, true, false><<<2048, 256, 0, stream>>>(
                    vin, vout, f16c, AB, fuse_w, fuse_b, maps, out, s);
        }
        __half2* t = vin; vin = vout; vout = t;
    }
}

// Round 7
// 609.634 us; speedup vs baseline: 1.3955x; 1.0883x over previous
//
#include <hip/hip_runtime.h>
#include <hip/hip_fp16.h>

#define H 256
#define W 256
#define BS 8
#define IC 16          // in_ch (flow fields per batch; also out channels)
#define OCH 32         // conv output channels = 2*IC
#define NSTEPS 7
#define PLANE (H*W)            // 65536
#define NFIELDS (BS*IC)        // 128
#define BN_N (BS*PLANE)        // 524288 elements per BN channel
#define BN_EPS 1e-5f

// ---------------------------------------------------------------------------
// K0: transpose vec_w [oc][ic][3][3] -> wT [ic*9+k][oc]
// ---------------------------------------------------------------------------
__global__ void transpose_w_kernel(const float* __restrict__ w,
                                   float* __restrict__ wT) {
    for (int idx = threadIdx.x; idx < OCH * IC * 9; idx += blockDim.x) {
        int oc  = idx / (IC * 9);
        int rem = idx - oc * (IC * 9);
        wT[rem * OCH + oc] = w[idx];
    }
}

// ---------------------------------------------------------------------------
// K1: 3x3 conv (16->32) + bias -> half2 flow fields + fp16 copy of f,
// with the BN sum/sumsq reduction fused (wave shfl-reduce of in-register
// acc + 64 atomics per block). Deletes the separate stats kernel.
// ---------------------------------------------------------------------------
__global__ __launch_bounds__(256, 6) void conv_kernel(
    const float* __restrict__ f, const float* __restrict__ wT,
    const float* __restrict__ vec_b, __half2* __restrict__ vec_out,
    __half* __restrict__ f16c, float* __restrict__ stats) {
    __shared__ float sf[8][18][19];
    __shared__ float redS[4][OCH];
    __shared__ float redQ[4][OCH];

    int blk = blockIdx.x;              // 2048
    int b   = blk >> 8;
    int rem = blk & 255;
    int ty0 = (rem >> 4) * 16;
    int tx0 = (rem & 15) * 16;
    int tid = threadIdx.x;
    int ty  = tid >> 4, tx = tid & 15;
    int y = ty0 + ty, x = tx0 + tx;

    float acc[OCH];
#pragma unroll
    for (int oc = 0; oc < OCH; ++oc) acc[oc] = vec_b[oc];

    for (int half = 0; half < 2; ++half) {
        if (half) __syncthreads();
        for (int idx = tid; idx < 8 * 18 * 18; idx += 256) {
            int ic = idx / 324;
            int r2 = idx - ic * 324;
            int r  = r2 / 18;
            int cc = r2 - r * 18;
            int gy = ty0 - 1 + r, gx = tx0 - 1 + cc;
            float v = 0.f;
            if (gy >= 0 && gy < H && gx >= 0 && gx < W)
                v = f[((size_t)(b * IC + half * 8 + ic) * H + gy) * W + gx];
            sf[ic][r][cc] = v;
        }
        __syncthreads();

#pragma unroll 2
        for (int ic = 0; ic < 8; ++ic) {
            f16c[(size_t)(b * IC + half * 8 + ic) * PLANE + y * W + x] =
                __float2half(sf[ic][ty + 1][tx + 1]);
#pragma unroll
            for (int k = 0; k < 9; ++k) {
                int ky = k / 3, kx = k - ky * 3;
                float fv = sf[ic][ty + ky][tx + kx];
                const float* wrow = wT + ((half * 8 + ic) * 9 + k) * OCH;
#pragma unroll
                for (int oc = 0; oc < OCH; ++oc)
                    acc[oc] = fmaf(fv, wrow[oc], acc[oc]);
            }
        }
    }

    // fused BN statistics: per-wave shfl reduce, then 64 atomics per block
    int wave = tid >> 6, lane = tid & 63;
#pragma unroll
    for (int oc = 0; oc < OCH; ++oc) {
        float s = acc[oc];
        float q = acc[oc] * acc[oc];
#pragma unroll
        for (int off = 32; off > 0; off >>= 1) {
            s += __shfl_down(s, off, 64);
            q += __shfl_down(q, off, 64);
        }
        if (lane == 0) { redS[wave][oc] = s; redQ[wave][oc] = q; }
    }
    __syncthreads();
    if (tid < OCH) {
        float ts = redS[0][tid] + redS[1][tid] + redS[2][tid] + redS[3][tid];
        float tq = redQ[0][tid] + redQ[1][tid] + redQ[2][tid] + redQ[3][tid];
        atomicAdd(stats + tid, ts);
        atomicAdd(stats + 32 + tid, tq);
    }

#pragma unroll
    for (int c = 0; c < IC; ++c) {
        vec_out[(size_t)(b * IC + c) * PLANE + y * W + x] =
            __float22half2_rn(make_float2(acc[2 * c], acc[2 * c + 1]));
    }
}

// ---------------------------------------------------------------------------
// K2: fold BN + 1/128 scale into per-channel affine.
// ---------------------------------------------------------------------------
__global__ void finalize_kernel(const float* __restrict__ stats,
                                const float* __restrict__ gamma,
                                const float* __restrict__ beta,
                                float* __restrict__ AB) {
    int ch = threadIdx.x;
    if (ch < 2 * IC) {
        const float invN = 1.f / (float)BN_N;
        float mean = stats[ch] * invN;
        float var  = stats[32 + ch] * invN - mean * mean;
        float rs   = rsqrtf(var + BN_EPS);
        float a    = gamma[ch] * rs;
        AB[ch]      = a * (1.f / 128.f);
        AB[32 + ch] = (beta[ch] - a * mean) * (1.f / 128.f);
    }
}

// ---------------------------------------------------------------------------
// bilinear tap setup: clamped offsets + validity-masked weights
// ---------------------------------------------------------------------------
__device__ __forceinline__ void tap_setup(float py, float px,
                                          int* o, float* wt) {
    float ffy = floorf(py), ffx = floorf(px);
    int y0 = (int)ffy, x0 = (int)ffx;
    float wy1 = py - ffy, wy0 = 1.f - wy1;
    float wx1 = px - ffx, wx0 = 1.f - wx1;
    bool vy0 = (unsigned)y0 < (unsigned)H, vy1 = (unsigned)(y0 + 1) < (unsigned)H;
    bool vx0 = (unsigned)x0 < (unsigned)W, vx1 = (unsigned)(x0 + 1) < (unsigned)W;
    int yc0 = min(max(y0, 0), H - 1), yc1 = min(max(y0 + 1, 0), H - 1);
    int xc0 = min(max(x0, 0), W - 1), xc1 = min(max(x0 + 1, 0), W - 1);
    o[0] = yc0 * W + xc0; o[1] = yc0 * W + xc1;
    o[2] = yc1 * W + xc0; o[3] = yc1 * W + xc1;
    wt[0] = (vy0 && vx0) ? wy0 * wx0 : 0.f;
    wt[1] = (vy0 && vx1) ? wy0 * wx1 : 0.f;
    wt[2] = (vy1 && vx0) ? wy1 * wx0 : 0.f;
    wt[3] = (vy1 && vx1) ? wy1 * wx1 : 0.f;
}

// ---------------------------------------------------------------------------
// K3: one scaling-and-squaring step on half2 deforms + fused f16 f-warp +
// incremental fuse-matvec into a cache-hot fp16 accumulator (16 planes).
// FIRST: init accumulator with fuse bias. LAST: emit f32 out, no acc write.
// ---------------------------------------------------------------------------
template <bool FIRST, bool LAST>
__global__ __launch_bounds__(256) void step_kernel(
    const __half2* __restrict__ vin, __half2* __restrict__ vout,
    const __half* __restrict__ f16c, const float* __restrict__ AB,
    const float* __restrict__ fw, const float* __restrict__ fb,
    __half* __restrict__ accp, float* __restrict__ out, int step) {
    int blk = blockIdx.x;             // BS*H = 2048
    int b   = blk >> 8;
    int h   = blk & (H - 1);
    int tx  = threadIdx.x;
    int idx = h * W + tx;
    const size_t base = (size_t)b * IC * PLANE;

    float mv[IC];

#pragma unroll 2
    for (int g = 0; g < 4; ++g) {
        float a0j[4], b0j[4], a1j[4], b1j[4];
        float fy[4], fx[4];
        int   o[4][4];
        float wt[4][4];
        const __half2* pl[4];
        float2 vc[4];

#pragma unroll
        for (int j = 0; j < 4; ++j) {
            int c = 4 * g + j;
            pl[j] = vin + base + (size_t)c * PLANE;
            vc[j] = __half22float2(pl[j][idx]);
        }

#pragma unroll
        for (int j = 0; j < 4; ++j) {
            int c = 4 * g + j;
            if (FIRST) {
                a0j[j] = AB[2 * c];     b0j[j] = AB[32 + 2 * c];
                a1j[j] = AB[2 * c + 1]; b1j[j] = AB[32 + 2 * c + 1];
            }
            fy[j] = FIRST ? fmaf(a0j[j], vc[j].x, b0j[j]) : vc[j].x;
            fx[j] = FIRST ? fmaf(a1j[j], vc[j].y, b1j[j]) : vc[j].y;
            tap_setup((float)h + fy[j], (float)tx + fx[j], o[j], wt[j]);
        }

        float2 t[4][4];
#pragma unroll
        for (int j = 0; j < 4; ++j)
#pragma unroll
            for (int k = 0; k < 4; ++k)
                t[j][k] = __half22float2(pl[j][o[j][k]]);

        float ny[4], nx[4];
        int   po[4][4];
        float pw[4][4];
#pragma unroll
        for (int j = 0; j < 4; ++j) {
            int c = 4 * g + j;
            float Sy = wt[j][0] * t[j][0].x + wt[j][1] * t[j][1].x
                     + wt[j][2] * t[j][2].x + wt[j][3] * t[j][3].x;
            float Sx = wt[j][0] * t[j][0].y + wt[j][1] * t[j][1].y
                     + wt[j][2] * t[j][2].y + wt[j][3] * t[j][3].y;
            if (FIRST) {
                float Ws = wt[j][0] + wt[j][1] + wt[j][2] + wt[j][3];
                ny[j] = fy[j] + fmaf(a0j[j], Sy, b0j[j] * Ws);
                nx[j] = fx[j] + fmaf(a1j[j], Sx, b1j[j] * Ws);
            } else {
                ny[j] = fy[j] + Sy;
                nx[j] = fx[j] + Sx;
            }
            if (!LAST)
                vout[base + (size_t)c * PLANE + idx] =
                    __float22half2_rn(make_float2(ny[j], nx[j]));
            tap_setup((float)h + ny[j], (float)tx + nx[j], po[j], pw[j]);
        }

#pragma unroll
        for (int j = 0; j < 4; ++j) {
            int c = 4 * g + j;
            const __half* fp = f16c + base + (size_t)c * PLANE;
            mv[c] = pw[j][0] * __half2float(fp[po[j][0]])
                  + pw[j][1] * __half2float(fp[po[j][1]])
                  + pw[j][2] * __half2float(fp[po[j][2]])
                  + pw[j][3] * __half2float(fp[po[j][3]]);
        }
    }

    // incremental fuse: acc_o (+)= fw[o,:,step] . mv
    float prev[IC];
    if (!FIRST) {
#pragma unroll
        for (int o2 = 0; o2 < IC; ++o2)
            prev[o2] = __half2float(accp[base + (size_t)o2 * PLANE + idx]);
    }
#pragma unroll
    for (int o2 = 0; o2 < IC; ++o2) {
        float a = FIRST ? fb[o2] : prev[o2];
#pragma unroll
        for (int c = 0; c < IC; ++c)
            a = fmaf(fw[(o2 * IC + c) * NSTEPS + step], mv[c], a);
        if (LAST)
            out[base + (size_t)o2 * PLANE + idx] = a;
        else
            accp[base + (size_t)o2 * PLANE + idx] = __float2half(a);
    }
}

// ---------------------------------------------------------------------------
extern "C" void kernel_launch(void* const* d_in, const int* in_sizes, int n_in,
                              void* d_out, int out_size, void* d_ws,
                              size_t ws_size, hipStream_t stream) {
    const float* f      = (const float*)d_in[0];
    const float* vec_w  = (const float*)d_in[1];
    const float* vec_b  = (const float*)d_in[2];
    const float* gamma  = (const float*)d_in[3];
    const float* beta   = (const float*)d_in[4];
    const float* fuse_w = (const float*)d_in[5];
    const float* fuse_b = (const float*)d_in[6];
    float* out = (float*)d_out;

    // ws layout (bytes):
    //   buf0:  NFIELDS*PLANE half2  = 33.55 MB
    //   buf1:  NFIELDS*PLANE half2  = 33.55 MB
    //   f16c:  NFIELDS*PLANE half   = 16.78 MB
    //   accp:  NFIELDS*PLANE half   = 16.78 MB  (fuse accumulator)
    //   wT, stats/AB: small
    char* ws = (char*)d_ws;
    const size_t fieldBytes2 = (size_t)NFIELDS * PLANE * sizeof(__half2);
    const size_t fieldBytes1 = (size_t)NFIELDS * PLANE * sizeof(__half);
    __half2* buf0 = (__half2*)ws;
    __half2* buf1 = (__half2*)(ws + fieldBytes2);
    __half*  f16c = (__half*)(ws + 2 * fieldBytes2);
    __half*  accp = (__half*)(ws + 2 * fieldBytes2 + fieldBytes1);
    float*   wT   = (float*)(ws + 2 * fieldBytes2 + 2 * fieldBytes1);
    float*   stats = wT + OCH * IC * 9;
    float*   AB    = stats + 64;

    hipMemsetAsync(stats, 0, 64 * sizeof(float), stream);
    transpose_w_kernel<<<1, 512, 0, stream>>>(vec_w, wT);
    conv_kernel<<<2048, 256, 0, stream>>>(f, wT, vec_b, buf0, f16c, stats);
    finalize_kernel<<<1, 64, 0, stream>>>(stats, gamma, beta, AB);

    __half2* vin = buf0;
    __half2* vout = buf1;
    for (int s = 0; s < NSTEPS; ++s) {
        if (s == 0)
            step_kernel<true, false><<<2048, 256, 0, stream>>>(
                vin, vout, f16c, AB, fuse_w, fuse_b, accp, out, s);
        else if (s < NSTEPS - 1)
            step_kernel<false, false><<<2048, 256, 0, stream>>>(
                vin, vout, f16c, AB, fuse_w, fuse_b, accp, out, s);
        else
            step_kernel<false, true><<<2048, 256, 0, stream>>>(
                vin, vout, f16c, AB, fuse_w, fuse_b, accp, out, s);
        __half2* t = vin; vin = vout; vout = t;
    }
}

// Round 8
// 591.133 us; speedup vs baseline: 1.4392x; 1.0313x over previous
//
#include <hip/hip_runtime.h>
#include <hip/hip_fp16.h>

#define H 256
#define W 256
#define BS 8
#define IC 16          // in_ch (flow fields per batch; also out channels)
#define OCH 32         // conv output channels = 2*IC
#define NSTEPS 7
#define PLANE (H*W)            // 65536
#define NFIELDS (BS*IC)        // 128
#define BN_N (BS*PLANE)        // 524288 elements per BN channel
#define BN_EPS 1e-5f

// ---------------------------------------------------------------------------
// K0: transpose vec_w [oc][ic][3][3] -> wT [ic*9+k][oc]
// ---------------------------------------------------------------------------
__global__ void transpose_w_kernel(const float* __restrict__ w,
                                   float* __restrict__ wT) {
    for (int idx = threadIdx.x; idx < OCH * IC * 9; idx += blockDim.x) {
        int oc  = idx / (IC * 9);
        int rem = idx - oc * (IC * 9);
        wT[rem * OCH + oc] = w[idx];
    }
}

// ---------------------------------------------------------------------------
// K1: 3x3 conv (16->32) + bias -> half2 flow fields + fp16 copy of f.
// 32x16 tile, 2 px/thread, 32-wide thread rows (2-way LDS aliasing = free),
// input staged in two 8-channel halves (19.6 KB LDS).
// launch_bounds(256,4): VGPR cap 128 -> no spills (acc needs ~95).
// ---------------------------------------------------------------------------
__global__ __launch_bounds__(256, 4) void conv_kernel(
    const float* __restrict__ f, const float* __restrict__ wT,
    const float* __restrict__ vec_b, __half2* __restrict__ vec_out,
    __half* __restrict__ f16c) {
    __shared__ float sf[8][18][34];    // 19.58 KB

    int blk = blockIdx.x;              // 8 * 16 * 8 = 1024
    int b   = blk >> 7;
    int rem = blk & 127;
    int ty0 = (rem >> 3) * 16;
    int tx0 = (rem & 7) * 32;
    int tid = threadIdx.x;
    int tyl = tid >> 5, txl = tid & 31;   // tyl 0..7, txl 0..31
    int y0p = ty0 + tyl, y1p = ty0 + tyl + 8, x = tx0 + txl;

    float acc0[OCH], acc1[OCH];
#pragma unroll
    for (int oc = 0; oc < OCH; ++oc) { acc0[oc] = vec_b[oc]; acc1[oc] = vec_b[oc]; }

    for (int half = 0; half < 2; ++half) {
        if (half) __syncthreads();
        for (int idx = tid; idx < 8 * 18 * 34; idx += 256) {
            int ic = idx / 612;
            int r2 = idx - ic * 612;
            int r  = r2 / 34;
            int cc = r2 - r * 34;
            int gy = ty0 - 1 + r, gx = tx0 - 1 + cc;
            float v = 0.f;
            if (gy >= 0 && gy < H && gx >= 0 && gx < W)
                v = f[((size_t)(b * IC + half * 8 + ic) * H + gy) * W + gx];
            sf[ic][r][cc] = v;
        }
        __syncthreads();

#pragma unroll 2
        for (int ic = 0; ic < 8; ++ic) {
            // fp16 copy of f for the gather passes (center pixels)
            size_t fb16 = (size_t)(b * IC + half * 8 + ic) * PLANE;
            f16c[fb16 + y0p * W + x] = __float2half(sf[ic][tyl + 1][txl + 1]);
            f16c[fb16 + y1p * W + x] = __float2half(sf[ic][tyl + 9][txl + 1]);
#pragma unroll
            for (int k = 0; k < 9; ++k) {
                int ky = k / 3, kx = k - ky * 3;
                float fv0 = sf[ic][tyl + ky][txl + kx];
                float fv1 = sf[ic][tyl + 8 + ky][txl + kx];
                const float* wrow = wT + ((half * 8 + ic) * 9 + k) * OCH;
#pragma unroll
                for (int oc = 0; oc < OCH; ++oc) {
                    float wv = wrow[oc];
                    acc0[oc] = fmaf(fv0, wv, acc0[oc]);
                    acc1[oc] = fmaf(fv1, wv, acc1[oc]);
                }
            }
        }
    }

#pragma unroll
    for (int c = 0; c < IC; ++c) {
        size_t pb = (size_t)(b * IC + c) * PLANE;
        vec_out[pb + y0p * W + x] =
            __float22half2_rn(make_float2(acc0[2 * c], acc0[2 * c + 1]));
        vec_out[pb + y1p * W + x] =
            __float22half2_rn(make_float2(acc1[2 * c], acc1[2 * c + 1]));
    }
}

// ---------------------------------------------------------------------------
// K2: per-channel sum / sumsq over the half2 conv output.
// ---------------------------------------------------------------------------
__global__ __launch_bounds__(256) void stats_kernel(
    const __half2* __restrict__ vec, float* __restrict__ stats) {
    int blk   = blockIdx.x;            // NFIELDS*16 = 2048
    int n     = blk >> 4;
    int chunk = blk & 15;
    const __half2* p = vec + (size_t)n * PLANE + chunk * 4096;
    int tid = threadIdx.x;

    float s0 = 0.f, s1 = 0.f, q0 = 0.f, q1 = 0.f;
#pragma unroll 4
    for (int i = tid; i < 4096; i += 256) {
        float2 v = __half22float2(p[i]);
        s0 += v.x; s1 += v.y;
        q0 = fmaf(v.x, v.x, q0);
        q1 = fmaf(v.y, v.y, q1);
    }
#pragma unroll
    for (int off = 32; off > 0; off >>= 1) {
        s0 += __shfl_down(s0, off, 64);
        s1 += __shfl_down(s1, off, 64);
        q0 += __shfl_down(q0, off, 64);
        q1 += __shfl_down(q1, off, 64);
    }
    __shared__ float red[4][4];
    int wave = tid >> 6, lane = tid & 63;
    if (lane == 0) {
        red[wave][0] = s0; red[wave][1] = s1;
        red[wave][2] = q0; red[wave][3] = q1;
    }
    __syncthreads();
    if (tid == 0) {
        float t0 = 0.f, t1 = 0.f, t2 = 0.f, t3 = 0.f;
#pragma unroll
        for (int wv = 0; wv < 4; ++wv) {
            t0 += red[wv][0]; t1 += red[wv][1];
            t2 += red[wv][2]; t3 += red[wv][3];
        }
        int ch0 = 2 * (n & 15);
        atomicAdd(stats + ch0,          t0);
        atomicAdd(stats + ch0 + 1,      t1);
        atomicAdd(stats + 32 + ch0,     t2);
        atomicAdd(stats + 32 + ch0 + 1, t3);
    }
}

// ---------------------------------------------------------------------------
// K3: fold BN + 1/128 scale into per-channel affine.
// ---------------------------------------------------------------------------
__global__ void finalize_kernel(const float* __restrict__ stats,
                                const float* __restrict__ gamma,
                                const float* __restrict__ beta,
                                float* __restrict__ AB) {
    int ch = threadIdx.x;
    if (ch < 2 * IC) {
        const float invN = 1.f / (float)BN_N;
        float mean = stats[ch] * invN;
        float var  = stats[32 + ch] * invN - mean * mean;
        float rs   = rsqrtf(var + BN_EPS);
        float a    = gamma[ch] * rs;
        AB[ch]      = a * (1.f / 128.f);
        AB[32 + ch] = (beta[ch] - a * mean) * (1.f / 128.f);
    }
}

// ---------------------------------------------------------------------------
// bilinear tap setup: clamped offsets + validity-masked weights
// ---------------------------------------------------------------------------
__device__ __forceinline__ void tap_setup(float py, float px,
                                          int* o, float* wt) {
    float ffy = floorf(py), ffx = floorf(px);
    int y0 = (int)ffy, x0 = (int)ffx;
    float wy1 = py - ffy, wy0 = 1.f - wy1;
    float wx1 = px - ffx, wx0 = 1.f - wx1;
    bool vy0 = (unsigned)y0 < (unsigned)H, vy1 = (unsigned)(y0 + 1) < (unsigned)H;
    bool vx0 = (unsigned)x0 < (unsigned)W, vx1 = (unsigned)(x0 + 1) < (unsigned)W;
    int yc0 = min(max(y0, 0), H - 1), yc1 = min(max(y0 + 1, 0), H - 1);
    int xc0 = min(max(x0, 0), W - 1), xc1 = min(max(x0 + 1, 0), W - 1);
    o[0] = yc0 * W + xc0; o[1] = yc0 * W + xc1;
    o[2] = yc1 * W + xc0; o[3] = yc1 * W + xc1;
    wt[0] = (vy0 && vx0) ? wy0 * wx0 : 0.f;
    wt[1] = (vy0 && vx1) ? wy0 * wx1 : 0.f;
    wt[2] = (vy1 && vx0) ? wy1 * wx0 : 0.f;
    wt[3] = (vy1 && vx1) ? wy1 * wx1 : 0.f;
}

// ---------------------------------------------------------------------------
// K4: one scaling-and-squaring step on half2 deforms + fused f16 f-warp +
// incremental fuse-matvec into a cache-hot fp16 accumulator (16 planes).
// FIRST: init accumulator with fuse bias. LAST: emit f32 out, no acc write.
// ---------------------------------------------------------------------------
template <bool FIRST, bool LAST>
__global__ __launch_bounds__(256) void step_kernel(
    const __half2* __restrict__ vin, __half2* __restrict__ vout,
    const __half* __restrict__ f16c, const float* __restrict__ AB,
    const float* __restrict__ fw, const float* __restrict__ fb,
    __half* __restrict__ accp, float* __restrict__ out, int step) {
    int blk = blockIdx.x;             // BS*H = 2048
    int b   = blk >> 8;
    int h   = blk & (H - 1);
    int tx  = threadIdx.x;
    int idx = h * W + tx;
    const size_t base = (size_t)b * IC * PLANE;

    float mv[IC];

#pragma unroll 2
    for (int g = 0; g < 4; ++g) {
        float a0j[4], b0j[4], a1j[4], b1j[4];
        float fy[4], fx[4];
        int   o[4][4];
        float wt[4][4];
        const __half2* pl[4];
        float2 vc[4];

#pragma unroll
        for (int j = 0; j < 4; ++j) {
            int c = 4 * g + j;
            pl[j] = vin + base + (size_t)c * PLANE;
            vc[j] = __half22float2(pl[j][idx]);
        }

#pragma unroll
        for (int j = 0; j < 4; ++j) {
            int c = 4 * g + j;
            if (FIRST) {
                a0j[j] = AB[2 * c];     b0j[j] = AB[32 + 2 * c];
                a1j[j] = AB[2 * c + 1]; b1j[j] = AB[32 + 2 * c + 1];
            }
            fy[j] = FIRST ? fmaf(a0j[j], vc[j].x, b0j[j]) : vc[j].x;
            fx[j] = FIRST ? fmaf(a1j[j], vc[j].y, b1j[j]) : vc[j].y;
            tap_setup((float)h + fy[j], (float)tx + fx[j], o[j], wt[j]);
        }

        float2 t[4][4];
#pragma unroll
        for (int j = 0; j < 4; ++j)
#pragma unroll
            for (int k = 0; k < 4; ++k)
                t[j][k] = __half22float2(pl[j][o[j][k]]);

        float ny[4], nx[4];
        int   po[4][4];
        float pw[4][4];
#pragma unroll
        for (int j = 0; j < 4; ++j) {
            int c = 4 * g + j;
            float Sy = wt[j][0] * t[j][0].x + wt[j][1] * t[j][1].x
                     + wt[j][2] * t[j][2].x + wt[j][3] * t[j][3].x;
            float Sx = wt[j][0] * t[j][0].y + wt[j][1] * t[j][1].y
                     + wt[j][2] * t[j][2].y + wt[j][3] * t[j][3].y;
            if (FIRST) {
                float Ws = wt[j][0] + wt[j][1] + wt[j][2] + wt[j][3];
                ny[j] = fy[j] + fmaf(a0j[j], Sy, b0j[j] * Ws);
                nx[j] = fx[j] + fmaf(a1j[j], Sx, b1j[j] * Ws);
            } else {
                ny[j] = fy[j] + Sy;
                nx[j] = fx[j] + Sx;
            }
            if (!LAST)
                vout[base + (size_t)c * PLANE + idx] =
                    __float22half2_rn(make_float2(ny[j], nx[j]));
            tap_setup((float)h + ny[j], (float)tx + nx[j], po[j], pw[j]);
        }

#pragma unroll
        for (int j = 0; j < 4; ++j) {
            int c = 4 * g + j;
            const __half* fp = f16c + base + (size_t)c * PLANE;
            mv[c] = pw[j][0] * __half2float(fp[po[j][0]])
                  + pw[j][1] * __half2float(fp[po[j][1]])
                  + pw[j][2] * __half2float(fp[po[j][2]])
                  + pw[j][3] * __half2float(fp[po[j][3]]);
        }
    }

    // incremental fuse: acc_o (+)= fw[o,:,step] . mv
    float prev[IC];
    if (!FIRST) {
#pragma unroll
        for (int o2 = 0; o2 < IC; ++o2)
            prev[o2] = __half2float(accp[base + (size_t)o2 * PLANE + idx]);
    }
#pragma unroll
    for (int o2 = 0; o2 < IC; ++o2) {
        float a = FIRST ? fb[o2] : prev[o2];
#pragma unroll
        for (int c = 0; c < IC; ++c)
            a = fmaf(fw[(o2 * IC + c) * NSTEPS + step], mv[c], a);
        if (LAST)
            out[base + (size_t)o2 * PLANE + idx] = a;
        else
            accp[base + (size_t)o2 * PLANE + idx] = __float2half(a);
    }
}

// ---------------------------------------------------------------------------
extern "C" void kernel_launch(void* const* d_in, const int* in_sizes, int n_in,
                              void* d_out, int out_size, void* d_ws,
                              size_t ws_size, hipStream_t stream) {
    const float* f      = (const float*)d_in[0];
    const float* vec_w  = (const float*)d_in[1];
    const float* vec_b  = (const float*)d_in[2];
    const float* gamma  = (const float*)d_in[3];
    const float* beta   = (const float*)d_in[4];
    const float* fuse_w = (const float*)d_in[5];
    const float* fuse_b = (const float*)d_in[6];
    float* out = (float*)d_out;

    // ws layout (bytes):
    //   buf0:  NFIELDS*PLANE half2  = 33.55 MB
    //   buf1:  NFIELDS*PLANE half2  = 33.55 MB
    //   f16c:  NFIELDS*PLANE half   = 16.78 MB
    //   accp:  NFIELDS*PLANE half   = 16.78 MB  (fuse accumulator)
    //   wT, stats/AB: small
    char* ws = (char*)d_ws;
    const size_t fieldBytes2 = (size_t)NFIELDS * PLANE * sizeof(__half2);
    const size_t fieldBytes1 = (size_t)NFIELDS * PLANE * sizeof(__half);
    __half2* buf0 = (__half2*)ws;
    __half2* buf1 = (__half2*)(ws + fieldBytes2);
    __half*  f16c = (__half*)(ws + 2 * fieldBytes2);
    __half*  accp = (__half*)(ws + 2 * fieldBytes2 + fieldBytes1);
    float*   wT   = (float*)(ws + 2 * fieldBytes2 + 2 * fieldBytes1);
    float*   stats = wT + OCH * IC * 9;
    float*   AB    = stats + 64;

    hipMemsetAsync(stats, 0, 64 * sizeof(float), stream);
    transpose_w_kernel<<<1, 512, 0, stream>>>(vec_w, wT);
    conv_kernel<<<1024, 256, 0, stream>>>(f, wT, vec_b, buf0, f16c);
    stats_kernel<<<NFIELDS * 16, 256, 0, stream>>>(buf0, stats);
    finalize_kernel<<<1, 64, 0, stream>>>(stats, gamma, beta, AB);

    __half2* vin = buf0;
    __half2* vout = buf1;
    for (int s = 0; s < NSTEPS; ++s) {
        if (s == 0)
            step_kernel<true, false><<<2048, 256, 0, stream>>>(
                vin, vout, f16c, AB, fuse_w, fuse_b, accp, out, s);
        else if (s < NSTEPS - 1)
            step_kernel<false, false><<<2048, 256, 0, stream>>>(
                vin, vout, f16c, AB, fuse_w, fuse_b, accp, out, s);
        else
            step_kernel<false, true><<<2048, 256, 0, stream>>>(
                vin, vout, f16c, AB, fuse_w, fuse_b, accp, out, s);
        __half2* t = vin; vin = vout; vout = t;
    }
}

// Round 9
// 560.663 us; speedup vs baseline: 1.5174x; 1.0543x over previous
//
#include <hip/hip_runtime.h>
#include <hip/hip_fp16.h>

#define H 256
#define W 256
#define BS 8
#define IC 16          // in_ch (flow fields per batch; also out channels)
#define OCH 32         // conv output channels = 2*IC
#define NSTEPS 7
#define PLANE (H*W)            // 65536
#define NFIELDS (BS*IC)        // 128
#define BN_N (BS*PLANE)        // 524288 elements per BN channel
#define BN_EPS 1e-5f

// ---------------------------------------------------------------------------
// K0: transpose vec_w [oc][ic][3][3] -> wT [ic*9+k][oc]
// ---------------------------------------------------------------------------
__global__ void transpose_w_kernel(const float* __restrict__ w,
                                   float* __restrict__ wT) {
    for (int idx = threadIdx.x; idx < OCH * IC * 9; idx += blockDim.x) {
        int oc  = idx / (IC * 9);
        int rem = idx - oc * (IC * 9);
        wT[rem * OCH + oc] = w[idx];
    }
}

// ---------------------------------------------------------------------------
// K1: 3x3 conv (16->32) + bias -> half2 flow fields + fp16 copy of f.
// 32x16 tile, 2 px/thread. XCD-band swizzle: XCD (blk&7) owns rows
// [32*xcd, 32*xcd+32) of every batch, matching the step kernels' bands.
// ---------------------------------------------------------------------------
__global__ __launch_bounds__(256, 4) void conv_kernel(
    const float* __restrict__ f, const float* __restrict__ wT,
    const float* __restrict__ vec_b, __half2* __restrict__ vec_out,
    __half* __restrict__ f16c) {
    __shared__ float sf[8][18][34];    // 19.58 KB

    int blk = blockIdx.x;              // 1024
    int xcd = blk & 7;
    int i   = blk >> 3;                // 0..127
    int b   = i >> 4;                  // 0..7
    int j   = i & 15;
    int ty0 = ((xcd << 1) | (j >> 3)) * 16;   // rows 32*xcd .. 32*xcd+31
    int tx0 = (j & 7) * 32;
    int tid = threadIdx.x;
    int tyl = tid >> 5, txl = tid & 31;
    int y0p = ty0 + tyl, y1p = ty0 + tyl + 8, x = tx0 + txl;

    float acc0[OCH], acc1[OCH];
#pragma unroll
    for (int oc = 0; oc < OCH; ++oc) { acc0[oc] = vec_b[oc]; acc1[oc] = vec_b[oc]; }

    for (int half = 0; half < 2; ++half) {
        if (half) __syncthreads();
        for (int idx = tid; idx < 8 * 18 * 34; idx += 256) {
            int ic = idx / 612;
            int r2 = idx - ic * 612;
            int r  = r2 / 34;
            int cc = r2 - r * 34;
            int gy = ty0 - 1 + r, gx = tx0 - 1 + cc;
            float v = 0.f;
            if (gy >= 0 && gy < H && gx >= 0 && gx < W)
                v = f[((size_t)(b * IC + half * 8 + ic) * H + gy) * W + gx];
            sf[ic][r][cc] = v;
        }
        __syncthreads();

#pragma unroll 2
        for (int ic = 0; ic < 8; ++ic) {
            size_t fb16 = (size_t)(b * IC + half * 8 + ic) * PLANE;
            f16c[fb16 + y0p * W + x] = __float2half(sf[ic][tyl + 1][txl + 1]);
            f16c[fb16 + y1p * W + x] = __float2half(sf[ic][tyl + 9][txl + 1]);
#pragma unroll
            for (int k = 0; k < 9; ++k) {
                int ky = k / 3, kx = k - ky * 3;
                float fv0 = sf[ic][tyl + ky][txl + kx];
                float fv1 = sf[ic][tyl + 8 + ky][txl + kx];
                const float* wrow = wT + ((half * 8 + ic) * 9 + k) * OCH;
#pragma unroll
                for (int oc = 0; oc < OCH; ++oc) {
                    float wv = wrow[oc];
                    acc0[oc] = fmaf(fv0, wv, acc0[oc]);
                    acc1[oc] = fmaf(fv1, wv, acc1[oc]);
                }
            }
        }
    }

#pragma unroll
    for (int c = 0; c < IC; ++c) {
        size_t pb = (size_t)(b * IC + c) * PLANE;
        vec_out[pb + y0p * W + x] =
            __float22half2_rn(make_float2(acc0[2 * c], acc0[2 * c + 1]));
        vec_out[pb + y1p * W + x] =
            __float22half2_rn(make_float2(acc1[2 * c], acc1[2 * c + 1]));
    }
}

// ---------------------------------------------------------------------------
// K2: per-channel sum / sumsq over the half2 conv output.
// ---------------------------------------------------------------------------
__global__ __launch_bounds__(256) void stats_kernel(
    const __half2* __restrict__ vec, float* __restrict__ stats) {
    int blk   = blockIdx.x;            // NFIELDS*16 = 2048
    int n     = blk >> 4;
    int chunk = blk & 15;
    const __half2* p = vec + (size_t)n * PLANE + chunk * 4096;
    int tid = threadIdx.x;

    float s0 = 0.f, s1 = 0.f, q0 = 0.f, q1 = 0.f;
#pragma unroll 4
    for (int i = tid; i < 4096; i += 256) {
        float2 v = __half22float2(p[i]);
        s0 += v.x; s1 += v.y;
        q0 = fmaf(v.x, v.x, q0);
        q1 = fmaf(v.y, v.y, q1);
    }
#pragma unroll
    for (int off = 32; off > 0; off >>= 1) {
        s0 += __shfl_down(s0, off, 64);
        s1 += __shfl_down(s1, off, 64);
        q0 += __shfl_down(q0, off, 64);
        q1 += __shfl_down(q1, off, 64);
    }
    __shared__ float red[4][4];
    int wave = tid >> 6, lane = tid & 63;
    if (lane == 0) {
        red[wave][0] = s0; red[wave][1] = s1;
        red[wave][2] = q0; red[wave][3] = q1;
    }
    __syncthreads();
    if (tid == 0) {
        float t0 = 0.f, t1 = 0.f, t2 = 0.f, t3 = 0.f;
#pragma unroll
        for (int wv = 0; wv < 4; ++wv) {
            t0 += red[wv][0]; t1 += red[wv][1];
            t2 += red[wv][2]; t3 += red[wv][3];
        }
        int ch0 = 2 * (n & 15);
        atomicAdd(stats + ch0,          t0);
        atomicAdd(stats + ch0 + 1,      t1);
        atomicAdd(stats + 32 + ch0,     t2);
        atomicAdd(stats + 32 + ch0 + 1, t3);
    }
}

// ---------------------------------------------------------------------------
// K3: fold BN + 1/128 scale into per-channel affine.
// ---------------------------------------------------------------------------
__global__ void finalize_kernel(const float* __restrict__ stats,
                                const float* __restrict__ gamma,
                                const float* __restrict__ beta,
                                float* __restrict__ AB) {
    int ch = threadIdx.x;
    if (ch < 2 * IC) {
        const float invN = 1.f / (float)BN_N;
        float mean = stats[ch] * invN;
        float var  = stats[32 + ch] * invN - mean * mean;
        float rs   = rsqrtf(var + BN_EPS);
        float a    = gamma[ch] * rs;
        AB[ch]      = a * (1.f / 128.f);
        AB[32 + ch] = (beta[ch] - a * mean) * (1.f / 128.f);
    }
}

// ---------------------------------------------------------------------------
// bilinear tap setup: clamped offsets + validity-masked weights
// ---------------------------------------------------------------------------
__device__ __forceinline__ void tap_setup(float py, float px,
                                          int* o, float* wt) {
    float ffy = floorf(py), ffx = floorf(px);
    int y0 = (int)ffy, x0 = (int)ffx;
    float wy1 = py - ffy, wy0 = 1.f - wy1;
    float wx1 = px - ffx, wx0 = 1.f - wx1;
    bool vy0 = (unsigned)y0 < (unsigned)H, vy1 = (unsigned)(y0 + 1) < (unsigned)H;
    bool vx0 = (unsigned)x0 < (unsigned)W, vx1 = (unsigned)(x0 + 1) < (unsigned)W;
    int yc0 = min(max(y0, 0), H - 1), yc1 = min(max(y0 + 1, 0), H - 1);
    int xc0 = min(max(x0, 0), W - 1), xc1 = min(max(x0 + 1, 0), W - 1);
    o[0] = yc0 * W + xc0; o[1] = yc0 * W + xc1;
    o[2] = yc1 * W + xc0; o[3] = yc1 * W + xc1;
    wt[0] = (vy0 && vx0) ? wy0 * wx0 : 0.f;
    wt[1] = (vy0 && vx1) ? wy0 * wx1 : 0.f;
    wt[2] = (vy1 && vx0) ? wy1 * wx0 : 0.f;
    wt[3] = (vy1 && vx1) ? wy1 * wx1 : 0.f;
}

// ---------------------------------------------------------------------------
// K4: one scaling-and-squaring step on half2 deforms + fused f16 f-warp +
// incremental fuse-matvec into an interleaved fp16 accumulator
// accp[(b*PLANE+idx)*IC + o] (vectorized 2x dwordx4 RMW).
// XCD-band swizzle: XCD (blk&7) owns rows [32*xcd, 32*xcd+32) of all batches.
// ---------------------------------------------------------------------------
template <bool FIRST, bool LAST>
__global__ __launch_bounds__(256) void step_kernel(
    const __half2* __restrict__ vin, __half2* __restrict__ vout,
    const __half* __restrict__ f16c, const float* __restrict__ AB,
    const float* __restrict__ fw, const float* __restrict__ fb,
    __half* __restrict__ accp, float* __restrict__ out, int step) {
    int blk = blockIdx.x;             // BS*H = 2048
    int xcd = blk & 7;
    int i   = blk >> 3;               // 0..255
    int b   = i >> 5;                 // 0..7
    int h   = (xcd << 5) | (i & 31);  // rows 32*xcd .. 32*xcd+31
    int tx  = threadIdx.x;
    int idx = h * W + tx;
    const size_t base = (size_t)b * IC * PLANE;

    float mv[IC];

#pragma unroll 2
    for (int g = 0; g < 4; ++g) {
        float a0j[4], b0j[4], a1j[4], b1j[4];
        float fy[4], fx[4];
        int   o[4][4];
        float wt[4][4];
        const __half2* pl[4];
        float2 vc[4];

#pragma unroll
        for (int j = 0; j < 4; ++j) {
            int c = 4 * g + j;
            pl[j] = vin + base + (size_t)c * PLANE;
            vc[j] = __half22float2(pl[j][idx]);
        }

#pragma unroll
        for (int j = 0; j < 4; ++j) {
            int c = 4 * g + j;
            if (FIRST) {
                a0j[j] = AB[2 * c];     b0j[j] = AB[32 + 2 * c];
                a1j[j] = AB[2 * c + 1]; b1j[j] = AB[32 + 2 * c + 1];
            }
            fy[j] = FIRST ? fmaf(a0j[j], vc[j].x, b0j[j]) : vc[j].x;
            fx[j] = FIRST ? fmaf(a1j[j], vc[j].y, b1j[j]) : vc[j].y;
            tap_setup((float)h + fy[j], (float)tx + fx[j], o[j], wt[j]);
        }

        float2 t[4][4];
#pragma unroll
        for (int j = 0; j < 4; ++j)
#pragma unroll
            for (int k = 0; k < 4; ++k)
                t[j][k] = __half22float2(pl[j][o[j][k]]);

        float ny[4], nx[4];
        int   po[4][4];
        float pw[4][4];
#pragma unroll
        for (int j = 0; j < 4; ++j) {
            int c = 4 * g + j;
            float Sy = wt[j][0] * t[j][0].x + wt[j][1] * t[j][1].x
                     + wt[j][2] * t[j][2].x + wt[j][3] * t[j][3].x;
            float Sx = wt[j][0] * t[j][0].y + wt[j][1] * t[j][1].y
                     + wt[j][2] * t[j][2].y + wt[j][3] * t[j][3].y;
            if (FIRST) {
                float Ws = wt[j][0] + wt[j][1] + wt[j][2] + wt[j][3];
                ny[j] = fy[j] + fmaf(a0j[j], Sy, b0j[j] * Ws);
                nx[j] = fx[j] + fmaf(a1j[j], Sx, b1j[j] * Ws);
            } else {
                ny[j] = fy[j] + Sy;
                nx[j] = fx[j] + Sx;
            }
            if (!LAST)
                vout[base + (size_t)c * PLANE + idx] =
                    __float22half2_rn(make_float2(ny[j], nx[j]));
            tap_setup((float)h + ny[j], (float)tx + nx[j], po[j], pw[j]);
        }

#pragma unroll
        for (int j = 0; j < 4; ++j) {
            int c = 4 * g + j;
            const __half* fp = f16c + base + (size_t)c * PLANE;
            mv[c] = pw[j][0] * __half2float(fp[po[j][0]])
                  + pw[j][1] * __half2float(fp[po[j][1]])
                  + pw[j][2] * __half2float(fp[po[j][2]])
                  + pw[j][3] * __half2float(fp[po[j][3]]);
        }
    }

    // incremental fuse: acc_o (+)= fw[o,:,step] . mv  (interleaved layout)
    __half* ap = accp + ((size_t)b * PLANE + idx) * IC;
    float prev[IC];
    if (!FIRST) {
        float4 p0 = ((const float4*)ap)[0];
        float4 p1 = ((const float4*)ap)[1];
        const __half2* ph = (const __half2*)&p0;
#pragma unroll
        for (int k = 0; k < 4; ++k) {
            float2 v = __half22float2(ph[k]);
            prev[2 * k] = v.x; prev[2 * k + 1] = v.y;
        }
        const __half2* qh = (const __half2*)&p1;
#pragma unroll
        for (int k = 0; k < 4; ++k) {
            float2 v = __half22float2(qh[k]);
            prev[8 + 2 * k] = v.x; prev[8 + 2 * k + 1] = v.y;
        }
    }

    float a[IC];
#pragma unroll
    for (int o2 = 0; o2 < IC; ++o2) {
        a[o2] = FIRST ? fb[o2] : prev[o2];
#pragma unroll
        for (int c = 0; c < IC; ++c)
            a[o2] = fmaf(fw[(o2 * IC + c) * NSTEPS + step], mv[c], a[o2]);
    }

    if (LAST) {
#pragma unroll
        for (int o2 = 0; o2 < IC; ++o2)
            out[base + (size_t)o2 * PLANE + idx] = a[o2];
    } else {
        float4 s0, s1;
        __half2* sh = (__half2*)&s0;
#pragma unroll
        for (int k = 0; k < 4; ++k)
            sh[k] = __float22half2_rn(make_float2(a[2 * k], a[2 * k + 1]));
        __half2* th = (__half2*)&s1;
#pragma unroll
        for (int k = 0; k < 4; ++k)
            th[k] = __float22half2_rn(make_float2(a[8 + 2 * k], a[9 + 2 * k]));
        ((float4*)ap)[0] = s0;
        ((float4*)ap)[1] = s1;
    }
}

// ---------------------------------------------------------------------------
extern "C" void kernel_launch(void* const* d_in, const int* in_sizes, int n_in,
                              void* d_out, int out_size, void* d_ws,
                              size_t ws_size, hipStream_t stream) {
    const float* f      = (const float*)d_in[0];
    const float* vec_w  = (const float*)d_in[1];
    const float* vec_b  = (const float*)d_in[2];
    const float* gamma  = (const float*)d_in[3];
    const float* beta   = (const float*)d_in[4];
    const float* fuse_w = (const float*)d_in[5];
    const float* fuse_b = (const float*)d_in[6];
    float* out = (float*)d_out;

    // ws layout (bytes):
    //   buf0:  NFIELDS*PLANE half2  = 33.55 MB
    //   buf1:  NFIELDS*PLANE half2  = 33.55 MB
    //   f16c:  NFIELDS*PLANE half   = 16.78 MB
    //   accp:  NFIELDS*PLANE half   = 16.78 MB  (interleaved fuse accumulator)
    //   wT, stats/AB: small
    char* ws = (char*)d_ws;
    const size_t fieldBytes2 = (size_t)NFIELDS * PLANE * sizeof(__half2);
    const size_t fieldBytes1 = (size_t)NFIELDS * PLANE * sizeof(__half);
    __half2* buf0 = (__half2*)ws;
    __half2* buf1 = (__half2*)(ws + fieldBytes2);
    __half*  f16c = (__half*)(ws + 2 * fieldBytes2);
    __half*  accp = (__half*)(ws + 2 * fieldBytes2 + fieldBytes1);
    float*   wT   = (float*)(ws + 2 * fieldBytes2 + 2 * fieldBytes1);
    float*   stats = wT + OCH * IC * 9;
    float*   AB    = stats + 64;

    hipMemsetAsync(stats, 0, 64 * sizeof(float), stream);
    transpose_w_kernel<<<1, 512, 0, stream>>>(vec_w, wT);
    conv_kernel<<<1024, 256, 0, stream>>>(f, wT, vec_b, buf0, f16c);
    stats_kernel<<<NFIELDS * 16, 256, 0, stream>>>(buf0, stats);
    finalize_kernel<<<1, 64, 0, stream>>>(stats, gamma, beta, AB);

    __half2* vin = buf0;
    __half2* vout = buf1;
    for (int s = 0; s < NSTEPS; ++s) {
        if (s == 0)
            step_kernel<true, false><<<2048, 256, 0, stream>>>(
                vin, vout, f16c, AB, fuse_w, fuse_b, accp, out, s);
        else if (s < NSTEPS - 1)
            step_kernel<false, false><<<2048, 256, 0, stream>>>(
                vin, vout, f16c, AB, fuse_w, fuse_b, accp, out, s);
        else
            step_kernel<false, true><<<2048, 256, 0, stream>>>(
                vin, vout, f16c, AB, fuse_w, fuse_b, accp, out, s);
        __half2* t = vin; vin = vout; vout = t;
    }
}

// Round 10
// 500.750 us; speedup vs baseline: 1.6989x; 1.1196x over previous
//
#include <hip/hip_runtime.h>
#include <hip/hip_fp16.h>

#define H 256
#define W 256
#define BS 8
#define IC 16          // in_ch (flow fields per batch; also out channels)
#define OCH 32         // conv output channels = 2*IC
#define NSTEPS 7
#define PLANE (H*W)            // 65536
#define NFIELDS (BS*IC)        // 128
#define BN_N (BS*PLANE)        // 524288
#define BN_EPS 1e-5f
// padded plane: interior (y,x) at (y+1, x+1), pitch 260, rows 0..258 used
#define PW 260
#define PSZ (260 * 260)

// ---------------------------------------------------------------------------
// K0: vec_w [oc][ic][3][3] -> wTh [(ic*9+k)][p] as half2 pairs (oc 2p, 2p+1)
// ---------------------------------------------------------------------------
__global__ void transpose_w_kernel(const float* __restrict__ w,
                                   __half2* __restrict__ wTh) {
    for (int idx = threadIdx.x; idx < IC * 9 * 16; idx += blockDim.x) {
        int rc = idx >> 4;        // ic*9+k
        int p  = idx & 15;
        float lo = w[(2 * p) * (IC * 9) + rc];
        float hi = w[(2 * p + 1) * (IC * 9) + rc];
        wTh[idx] = __floats2half2_rn(lo, hi);
    }
}

// ---------------------------------------------------------------------------
// K1: zero the guard borders of the two padded step buffers + padded f16.
// Guard cells per plane: rows {0,257,258,259} full width, cols {0,257,258,259}
// for interior rows -> 2064 cells = PSZ - PLANE.
// ---------------------------------------------------------------------------
__global__ void guard_zero_kernel(unsigned* __restrict__ bufA,
                                  unsigned* __restrict__ bufB,
                                  unsigned short* __restrict__ f16p) {
    int p = blockIdx.x;           // 128 planes
    size_t pb = (size_t)p * PSZ;
    for (int i = threadIdx.x; i < 2064; i += blockDim.x) {
        int row, col;
        if (i < 1040) {
            int r = i / 260;
            row = (r == 0) ? 0 : 256 + r;     // 0,257,258,259
            col = i - r * 260;
        } else {
            int j = i - 1040;
            int c = j / 256;
            col = (c == 0) ? 0 : 256 + c;     // 0,257,258,259
            row = 1 + (j - c * 256);
        }
        size_t off = pb + (size_t)row * PW + col;
        bufA[off] = 0u;
        bufB[off] = 0u;
        f16p[off] = 0;
    }
}

// ---------------------------------------------------------------------------
// K2: 3x3 conv (16->32) + bias in PACKED FP16 (v_pk_fma_f16): half2 acc per
// oc-pair == exactly the output flow element. Also writes padded fp16 f copy.
// 32x16 tile, 2 px/thread, XCD-band swizzle on rows.
// ---------------------------------------------------------------------------
__global__ __launch_bounds__(256, 4) void conv_kernel(
    const float* __restrict__ f, const __half2* __restrict__ wTh,
    const float* __restrict__ vec_b, __half2* __restrict__ vec_out,
    __half* __restrict__ f16p) {
    __shared__ __half sf[8][18][34];   // 9.8 KB

    int blk = blockIdx.x;              // 1024
    int xcd = blk & 7;
    int i   = blk >> 3;
    int b   = i >> 4;
    int j   = i & 15;
    int ty0 = ((xcd << 1) | (j >> 3)) * 16;
    int tx0 = (j & 7) * 32;
    int tid = threadIdx.x;
    int tyl = tid >> 5, txl = tid & 31;
    int y0p = ty0 + tyl, y1p = ty0 + tyl + 8, x = tx0 + txl;

    __half2 acc0[16], acc1[16];
#pragma unroll
    for (int p = 0; p < 16; ++p) {
        __half2 bp = __floats2half2_rn(vec_b[2 * p], vec_b[2 * p + 1]);
        acc0[p] = bp; acc1[p] = bp;
    }

    for (int half = 0; half < 2; ++half) {
        if (half) __syncthreads();
        for (int idx = tid; idx < 8 * 18 * 34; idx += 256) {
            int ic = idx / 612;
            int r2 = idx - ic * 612;
            int r  = r2 / 34;
            int cc = r2 - r * 34;
            int gy = ty0 - 1 + r, gx = tx0 - 1 + cc;
            float v = 0.f;
            if (gy >= 0 && gy < H && gx >= 0 && gx < W)
                v = f[((size_t)(b * IC + half * 8 + ic) * H + gy) * W + gx];
            sf[ic][r][cc] = __float2half(v);
        }
        __syncthreads();

#pragma unroll 2
        for (int ic = 0; ic < 8; ++ic) {
            size_t fb16 = (size_t)(b * IC + half * 8 + ic) * PSZ;
            f16p[fb16 + (size_t)(y0p + 1) * PW + x + 1] = sf[ic][tyl + 1][txl + 1];
            f16p[fb16 + (size_t)(y1p + 1) * PW + x + 1] = sf[ic][tyl + 9][txl + 1];
#pragma unroll
            for (int k = 0; k < 9; ++k) {
                int ky = k / 3, kx = k - ky * 3;
                __half2 fv0 = __half2half2(sf[ic][tyl + ky][txl + kx]);
                __half2 fv1 = __half2half2(sf[ic][tyl + 8 + ky][txl + kx]);
                const __half2* wrow = wTh + ((half * 8 + ic) * 9 + k) * 16;
#pragma unroll
                for (int p = 0; p < 16; ++p) {
                    __half2 wv = wrow[p];
                    acc0[p] = __hfma2(fv0, wv, acc0[p]);
                    acc1[p] = __hfma2(fv1, wv, acc1[p]);
                }
            }
        }
    }

#pragma unroll
    for (int c = 0; c < IC; ++c) {
        size_t pb = (size_t)(b * IC + c) * PLANE;
        vec_out[pb + y0p * W + x] = acc0[c];
        vec_out[pb + y1p * W + x] = acc1[c];
    }
}

// ---------------------------------------------------------------------------
// K3: per-channel sum / sumsq over the half2 conv output (unpadded).
// ---------------------------------------------------------------------------
__global__ __launch_bounds__(256) void stats_kernel(
    const __half2* __restrict__ vec, float* __restrict__ stats) {
    int blk   = blockIdx.x;            // 2048
    int n     = blk >> 4;
    int chunk = blk & 15;
    const __half2* p = vec + (size_t)n * PLANE + chunk * 4096;
    int tid = threadIdx.x;

    float s0 = 0.f, s1 = 0.f, q0 = 0.f, q1 = 0.f;
#pragma unroll 4
    for (int i = tid; i < 4096; i += 256) {
        float2 v = __half22float2(p[i]);
        s0 += v.x; s1 += v.y;
        q0 = fmaf(v.x, v.x, q0);
        q1 = fmaf(v.y, v.y, q1);
    }
#pragma unroll
    for (int off = 32; off > 0; off >>= 1) {
        s0 += __shfl_down(s0, off, 64);
        s1 += __shfl_down(s1, off, 64);
        q0 += __shfl_down(q0, off, 64);
        q1 += __shfl_down(q1, off, 64);
    }
    __shared__ float red[4][4];
    int wave = tid >> 6, lane = tid & 63;
    if (lane == 0) {
        red[wave][0] = s0; red[wave][1] = s1;
        red[wave][2] = q0; red[wave][3] = q1;
    }
    __syncthreads();
    if (tid == 0) {
        float t0 = 0.f, t1 = 0.f, t2 = 0.f, t3 = 0.f;
#pragma unroll
        for (int wv = 0; wv < 4; ++wv) {
            t0 += red[wv][0]; t1 += red[wv][1];
            t2 += red[wv][2]; t3 += red[wv][3];
        }
        int ch0 = 2 * (n & 15);
        atomicAdd(stats + ch0,          t0);
        atomicAdd(stats + ch0 + 1,      t1);
        atomicAdd(stats + 32 + ch0,     t2);
        atomicAdd(stats + 32 + ch0 + 1, t3);
    }
}

// ---------------------------------------------------------------------------
// K4: fold BN + 1/128 scale into per-channel affine.
// ---------------------------------------------------------------------------
__global__ void finalize_kernel(const float* __restrict__ stats,
                                const float* __restrict__ gamma,
                                const float* __restrict__ beta,
                                float* __restrict__ AB) {
    int ch = threadIdx.x;
    if (ch < 2 * IC) {
        const float invN = 1.f / (float)BN_N;
        float mean = stats[ch] * invN;
        float var  = stats[32 + ch] * invN - mean * mean;
        float rs   = rsqrtf(var + BN_EPS);
        float a    = gamma[ch] * rs;
        AB[ch]      = a * (1.f / 128.f);
        AB[32 + ch] = (beta[ch] - a * mean) * (1.f / 128.f);
    }
}

// ---------------------------------------------------------------------------
// masked tap setup (unpadded planes; FIRST-step deform reads only)
// ---------------------------------------------------------------------------
__device__ __forceinline__ void tap_setup(float py, float px,
                                          int* o, float* wt) {
    float ffy = floorf(py), ffx = floorf(px);
    int y0 = (int)ffy, x0 = (int)ffx;
    float wy1 = py - ffy, wy0 = 1.f - wy1;
    float wx1 = px - ffx, wx0 = 1.f - wx1;
    bool vy0 = (unsigned)y0 < (unsigned)H, vy1 = (unsigned)(y0 + 1) < (unsigned)H;
    bool vx0 = (unsigned)x0 < (unsigned)W, vx1 = (unsigned)(x0 + 1) < (unsigned)W;
    int yc0 = min(max(y0, 0), H - 1), yc1 = min(max(y0 + 1, 0), H - 1);
    int xc0 = min(max(x0, 0), W - 1), xc1 = min(max(x0 + 1, 0), W - 1);
    o[0] = yc0 * W + xc0; o[1] = yc0 * W + xc1;
    o[2] = yc1 * W + xc0; o[3] = yc1 * W + xc1;
    wt[0] = (vy0 && vx0) ? wy0 * wx0 : 0.f;
    wt[1] = (vy0 && vx1) ? wy0 * wx1 : 0.f;
    wt[2] = (vy1 && vx0) ? wy1 * wx0 : 0.f;
    wt[3] = (vy1 && vx1) ? wy1 * wx1 : 0.f;
}

// ---------------------------------------------------------------------------
// fast tap setup for guard-padded planes: clamp coords into the zero guard,
// no validity masking needed. Returns base offset; taps at o, o+1, o+PW, o+PW+1.
// ---------------------------------------------------------------------------
__device__ __forceinline__ void tap_fast(float py, float px,
                                         int& o, float* wt) {
    float pyc = fminf(fmaxf(py, -1.f), 256.f);
    float pxc = fminf(fmaxf(px, -1.f), 256.f);
    float fy = floorf(pyc), fx = floorf(pxc);
    int y0 = (int)fy, x0 = (int)fx;
    float wy1 = pyc - fy, wy0 = 1.f - wy1;
    float wx1 = pxc - fx, wx0 = 1.f - wx1;
    o = (y0 + 1) * PW + (x0 + 1);
    wt[0] = wy0 * wx0; wt[1] = wy0 * wx1;
    wt[2] = wy1 * wx0; wt[3] = wy1 * wx1;
}

// ---------------------------------------------------------------------------
// K5: one squaring step + fused f-warp + incremental fuse matvec.
// FIRST: vin = raw conv (unpadded, masked taps + BN affine), vout padded.
// Mid/LAST: vin padded (fast taps). LAST: writes f32 out, no vout.
// ---------------------------------------------------------------------------
template <bool FIRST, bool LAST>
__global__ __launch_bounds__(256) void step_kernel(
    const __half2* __restrict__ vinRaw, const __half2* __restrict__ vinPad,
    __half2* __restrict__ voutPad, const __half* __restrict__ f16p,
    const float* __restrict__ AB, const float* __restrict__ fw,
    const float* __restrict__ fb, __half* __restrict__ accp,
    float* __restrict__ out, int step) {
    int blk = blockIdx.x;             // 2048
    int xcd = blk & 7;
    int i   = blk >> 3;
    int b   = i >> 5;
    int h   = (xcd << 5) | (i & 31);
    int tx  = threadIdx.x;
    int idx_raw = h * W + tx;
    int idx_pad = (h + 1) * PW + tx + 1;
    const size_t baseR = (size_t)b * IC * PLANE;
    const size_t baseP = (size_t)b * IC * PSZ;

    float mv[IC];

#pragma unroll 2
    for (int g = 0; g < 4; ++g) {
        float a0j[4], b0j[4], a1j[4], b1j[4];
        float fy[4], fx[4];
        float wt[4][4];
        int   ob[4];
        int   om[4][4];
        const __half2* pl[4];
        float2 vc[4];

#pragma unroll
        for (int j = 0; j < 4; ++j) {
            int c = 4 * g + j;
            if (FIRST) {
                pl[j] = vinRaw + baseR + (size_t)c * PLANE;
                vc[j] = __half22float2(pl[j][idx_raw]);
            } else {
                pl[j] = vinPad + baseP + (size_t)c * PSZ;
                vc[j] = __half22float2(pl[j][idx_pad]);
            }
        }

#pragma unroll
        for (int j = 0; j < 4; ++j) {
            int c = 4 * g + j;
            if (FIRST) {
                a0j[j] = AB[2 * c];     b0j[j] = AB[32 + 2 * c];
                a1j[j] = AB[2 * c + 1]; b1j[j] = AB[32 + 2 * c + 1];
                fy[j] = fmaf(a0j[j], vc[j].x, b0j[j]);
                fx[j] = fmaf(a1j[j], vc[j].y, b1j[j]);
                tap_setup((float)h + fy[j], (float)tx + fx[j], om[j], wt[j]);
            } else {
                fy[j] = vc[j].x;
                fx[j] = vc[j].y;
                tap_fast((float)h + fy[j], (float)tx + fx[j], ob[j], wt[j]);
            }
        }

        float2 t[4][4];
#pragma unroll
        for (int j = 0; j < 4; ++j) {
            if (FIRST) {
#pragma unroll
                for (int k = 0; k < 4; ++k)
                    t[j][k] = __half22float2(pl[j][om[j][k]]);
            } else {
                t[j][0] = __half22float2(pl[j][ob[j]]);
                t[j][1] = __half22float2(pl[j][ob[j] + 1]);
                t[j][2] = __half22float2(pl[j][ob[j] + PW]);
                t[j][3] = __half22float2(pl[j][ob[j] + PW + 1]);
            }
        }

        float ny[4], nx[4];
        int   pb_[4];
        float pw_[4][4];
#pragma unroll
        for (int j = 0; j < 4; ++j) {
            int c = 4 * g + j;
            float Sy = wt[j][0] * t[j][0].x + wt[j][1] * t[j][1].x
                     + wt[j][2] * t[j][2].x + wt[j][3] * t[j][3].x;
            float Sx = wt[j][0] * t[j][0].y + wt[j][1] * t[j][1].y
                     + wt[j][2] * t[j][2].y + wt[j][3] * t[j][3].y;
            if (FIRST) {
                float Ws = wt[j][0] + wt[j][1] + wt[j][2] + wt[j][3];
                ny[j] = fy[j] + fmaf(a0j[j], Sy, b0j[j] * Ws);
                nx[j] = fx[j] + fmaf(a1j[j], Sx, b1j[j] * Ws);
            } else {
                ny[j] = fy[j] + Sy;
                nx[j] = fx[j] + Sx;
            }
            if (!LAST)
                voutPad[baseP + (size_t)c * PSZ + idx_pad] =
                    __float22half2_rn(make_float2(ny[j], nx[j]));
            tap_fast((float)h + ny[j], (float)tx + nx[j], pb_[j], pw_[j]);
        }

#pragma unroll
        for (int j = 0; j < 4; ++j) {
            int c = 4 * g + j;
            const __half* fp = f16p + baseP + (size_t)c * PSZ;
            mv[c] = pw_[j][0] * __half2float(fp[pb_[j]])
                  + pw_[j][1] * __half2float(fp[pb_[j] + 1])
                  + pw_[j][2] * __half2float(fp[pb_[j] + PW])
                  + pw_[j][3] * __half2float(fp[pb_[j] + PW + 1]);
        }
    }

    // incremental fuse: acc_o (+)= fw[o,:,step] . mv  (interleaved accp)
    __half* ap = accp + ((size_t)b * PLANE + idx_raw) * IC;
    float prev[IC];
    if (!FIRST) {
        float4 p0 = ((const float4*)ap)[0];
        float4 p1 = ((const float4*)ap)[1];
        const __half2* ph = (const __half2*)&p0;
#pragma unroll
        for (int k = 0; k < 4; ++k) {
            float2 v = __half22float2(ph[k]);
            prev[2 * k] = v.x; prev[2 * k + 1] = v.y;
        }
        const __half2* qh = (const __half2*)&p1;
#pragma unroll
        for (int k = 0; k < 4; ++k) {
            float2 v = __half22float2(qh[k]);
            prev[8 + 2 * k] = v.x; prev[8 + 2 * k + 1] = v.y;
        }
    }

    float a[IC];
#pragma unroll
    for (int o2 = 0; o2 < IC; ++o2) {
        a[o2] = FIRST ? fb[o2] : prev[o2];
#pragma unroll
        for (int c = 0; c < IC; ++c)
            a[o2] = fmaf(fw[(o2 * IC + c) * NSTEPS + step], mv[c], a[o2]);
    }

    if (LAST) {
#pragma unroll
        for (int o2 = 0; o2 < IC; ++o2)
            out[baseR + (size_t)o2 * PLANE + idx_raw] = a[o2];
    } else {
        float4 s0, s1;
        __half2* sh = (__half2*)&s0;
#pragma unroll
        for (int k = 0; k < 4; ++k)
            sh[k] = __float22half2_rn(make_float2(a[2 * k], a[2 * k + 1]));
        __half2* th = (__half2*)&s1;
#pragma unroll
        for (int k = 0; k < 4; ++k)
            th[k] = __float22half2_rn(make_float2(a[8 + 2 * k], a[9 + 2 * k]));
        ((float4*)ap)[0] = s0;
        ((float4*)ap)[1] = s1;
    }
}

// ---------------------------------------------------------------------------
extern "C" void kernel_launch(void* const* d_in, const int* in_sizes, int n_in,
                              void* d_out, int out_size, void* d_ws,
                              size_t ws_size, hipStream_t stream) {
    const float* f      = (const float*)d_in[0];
    const float* vec_w  = (const float*)d_in[1];
    const float* vec_b  = (const float*)d_in[2];
    const float* gamma  = (const float*)d_in[3];
    const float* beta   = (const float*)d_in[4];
    const float* fuse_w = (const float*)d_in[5];
    const float* fuse_b = (const float*)d_in[6];
    float* out = (float*)d_out;

    // ws layout (bytes):
    //   bufRaw: NFIELDS*PLANE half2       = 33.55 MB (conv output, unpadded)
    //   bufA:   NFIELDS*PSZ half2         = 34.61 MB (padded ping)
    //   bufB:   NFIELDS*PSZ half2         = 34.61 MB (padded pong)
    //   f16p:   NFIELDS*PSZ half          = 17.31 MB (padded f copy)
    //   accp:   NFIELDS*PLANE half        = 16.78 MB (interleaved accumulator)
    //   wTh, stats/AB: small                          total ~137 MB
    char* ws = (char*)d_ws;
    const size_t rawB  = (size_t)NFIELDS * PLANE * sizeof(__half2);
    const size_t padB2 = (size_t)NFIELDS * PSZ * sizeof(__half2);
    const size_t padB1 = (size_t)NFIELDS * PSZ * sizeof(__half);
    const size_t accB  = (size_t)NFIELDS * PLANE * sizeof(__half);
    __half2* bufRaw = (__half2*)ws;
    __half2* bufA   = (__half2*)(ws + rawB);
    __half2* bufB   = (__half2*)(ws + rawB + padB2);
    __half*  f16p   = (__half*)(ws + rawB + 2 * padB2);
    __half*  accp   = (__half*)(ws + rawB + 2 * padB2 + padB1);
    __half2* wTh    = (__half2*)(ws + rawB + 2 * padB2 + padB1 + accB);
    float*   stats  = (float*)(wTh + IC * 9 * 16);
    float*   AB     = stats + 64;

    hipMemsetAsync(stats, 0, 64 * sizeof(float), stream);
    transpose_w_kernel<<<1, 512, 0, stream>>>(vec_w, wTh);
    guard_zero_kernel<<<NFIELDS, 256, 0, stream>>>(
        (unsigned*)bufA, (unsigned*)bufB, (unsigned short*)f16p);
    conv_kernel<<<1024, 256, 0, stream>>>(f, wTh, vec_b, bufRaw, f16p);
    stats_kernel<<<NFIELDS * 16, 256, 0, stream>>>(bufRaw, stats);
    finalize_kernel<<<1, 64, 0, stream>>>(stats, gamma, beta, AB);

    // s=0: bufRaw -> bufA; s odd: bufA -> bufB; s even>0: bufB -> bufA
    for (int s = 0; s < NSTEPS; ++s) {
        const __half2* vinPad = (s & 1) ? bufA : bufB;
        __half2*       voutP  = (s & 1) ? bufB : bufA;
        if (s == 0)
            step_kernel<true, false><<<2048, 256, 0, stream>>>(
                bufRaw, (const __half2*)nullptr, bufA, f16p, AB,
                fuse_w, fuse_b, accp, out, s);
        else if (s < NSTEPS - 1)
            step_kernel<false, false><<<2048, 256, 0, stream>>>(
                (const __half2*)nullptr, vinPad, voutP, f16p, AB,
                fuse_w, fuse_b, accp, out, s);
        else
            step_kernel<false, true><<<2048, 256, 0, stream>>>(
                (const __half2*)nullptr, vinPad, (__half2*)nullptr, f16p, AB,
                fuse_w, fuse_b, accp, out, s);
    }
}